// Round 4
// baseline (326.311 us; speedup 1.0000x reference)
//
#include <hip/hip_runtime.h>
#include <hip/hip_bf16.h>

#define B_SZ 4096
#define DZ   512
#define H_SZ 2048
#define DY   10

// c_k = C(64,k)/64^k  (binomial coefficients of (1+u/64)^64), c0=c1=1
#define C2 0.4921875f
#define C3 0.158935546875f
#define C4 0.037872314453125f
#define C5 ((float)(7624512.0/1073741824.0))
#define C6 ((float)(74974368.0/68719476736.0))

typedef __attribute__((ext_vector_type(8))) __bf16 bf16x8;
typedef __attribute__((ext_vector_type(4))) float  f32x4;
typedef __attribute__((ext_vector_type(8))) unsigned short us8;

__device__ inline unsigned short f2bf(float f) {
    unsigned u = __float_as_uint(f);
    u += 0x7fffu + ((u >> 16) & 1u);   // RTNE
    return (unsigned short)(u >> 16);
}
__device__ inline float bf2f(unsigned short s) {
    return __uint_as_float(((unsigned)s) << 16);
}

// global -> LDS direct 16B copy. LDS dest is wave-uniform base + lane*16
// (HW semantics): callers pre-apply the inverse XOR swizzle on the per-lane
// GLOBAL address and keep the LDS side linear (rule #21 pattern).
__device__ __forceinline__ void gl16(const void* g, void* l) {
    __builtin_amdgcn_global_load_lds(
        (const __attribute__((address_space(1))) unsigned int*)(size_t)g,
        (__attribute__((address_space(3))) unsigned int*)(unsigned)(size_t)l,
        16, 0, 0);
}

// Device-scope grid barrier (persistent kernel, grid <= 256 = #CUs so all
// blocks are co-resident by construction). Counter zeroed via memset node.
__device__ __forceinline__ void gridbar(unsigned* __restrict__ cnt,
                                        unsigned target) {
    __threadfence();                       // publish this thread's writes
    __syncthreads();                       // whole block fenced
    if (threadIdx.x == 0) {
        __hip_atomic_fetch_add(cnt, 1u, __ATOMIC_ACQ_REL,
                               __HIP_MEMORY_SCOPE_AGENT);
        while (__hip_atomic_load(cnt, __ATOMIC_ACQUIRE,
                                 __HIP_MEMORY_SCOPE_AGENT) < target)
            __builtin_amdgcn_s_sleep(8);
    }
    __syncthreads();
    __threadfence();                       // acquire: invalidate stale cache
}

// ===== 64x64 tile machinery (16 KB LDS) ====================================
union SqSmem {
    struct { unsigned short A[64 * 64]; unsigned short B[64 * 64]; } s; // 16 KB
    float epi[64 * 68];                                                 // 17.4 KB
};

// Stage a 64x64 bf16 tile into LDS layout lds[row*64 + (cc^(row&7))*8]
// via global_load_lds: linear LDS chunk o -> row=o>>3, src cc=(o&7)^(row&7).
__device__ __forceinline__ void stage64(const unsigned short* __restrict__ src,
                                        unsigned short* lds, int row_base,
                                        int kt, int t) {
    const int w = t >> 6, lane = t & 63;
#pragma unroll
    for (int i = 0; i < 2; ++i) {
        int o = w * 128 + i * 64 + lane;
        int row = o >> 3, cc = (o & 7) ^ (row & 7);
        gl16(&src[(size_t)(row_base + row) * 512 + kt * 64 + cc * 8],
             &lds[(size_t)(w * 128 + i * 64) * 8]);
    }
}

#define MFMA_STEP(acc)                                                        \
    {                                                                         \
        _Pragma("unroll")                                                     \
        for (int ks = 0; ks < 2; ++ks) {                                      \
            bf16x8 af[2], bfr[2];                                             \
            _Pragma("unroll")                                                 \
            for (int i = 0; i < 2; ++i) {                                     \
                int ra = wm + i * 16 + l16, ca = (ks * 4 + quad) ^ (ra & 7);  \
                af[i] = *(const bf16x8*)&sm.s.A[ra * 64 + ca * 8];            \
                int rb = wn + i * 16 + l16, cb = (ks * 4 + quad) ^ (rb & 7);  \
                bfr[i] = *(const bf16x8*)&sm.s.B[rb * 64 + cb * 8];           \
            }                                                                 \
            _Pragma("unroll")                                                 \
            for (int i = 0; i < 2; ++i)                                       \
                _Pragma("unroll")                                             \
                for (int j = 0; j < 2; ++j)                                   \
                    acc[i][j] = __builtin_amdgcn_mfma_f32_16x16x32_bf16(      \
                        af[i], bfr[j], acc[i][j], 0, 0, 0);                   \
        }                                                                     \
    }

#define ACC_TO_EPI(acc)                                                       \
    {                                                                         \
        _Pragma("unroll")                                                     \
        for (int i = 0; i < 2; ++i)                                           \
            _Pragma("unroll")                                                 \
            for (int j = 0; j < 2; ++j)                                       \
                _Pragma("unroll")                                             \
                for (int rr = 0; rr < 4; ++rr)                                \
                    sm.epi[(wm + i * 16 + quad * 4 + rr) * 68 +               \
                           wn + j * 16 + l16] = acc[i][j][rr];                \
        __syncthreads();                                                      \
    }

// gemm64_mfma: 64x64 tile of (Arows)·(Brows)^T, bf16 sources, K=512 -> sm.epi
__device__ inline void gemm64_mfma(const unsigned short* __restrict__ Arows,
                                   const unsigned short* __restrict__ Brows,
                                   int m0, int n0, int t, SqSmem& sm) {
    const int lane = t & 63, w = t >> 6, quad = lane >> 4, l16 = lane & 15;
    const int wm = (w & 1) * 32, wn = (w >> 1) * 32;
    f32x4 acc[2][2];
#pragma unroll
    for (int i = 0; i < 2; ++i)
#pragma unroll
        for (int j = 0; j < 2; ++j) acc[i][j] = (f32x4){0.f, 0.f, 0.f, 0.f};
    for (int kt = 0; kt < 8; ++kt) {
        stage64(Arows, sm.s.A, m0, kt, t);
        stage64(Brows, sm.s.B, n0, kt, t);
        __syncthreads();
        MFMA_STEP(acc)
        __syncthreads();
    }
    ACC_TO_EPI(acc)
}

// gemm64_combineB: 64x64 tile of (Arows)·(cx·X + cy·Y)^T; A via gl16,
// B combined in VGPRs + swizzled ds_write (r3-proven staging pattern).
__device__ inline void gemm64_combineB(const unsigned short* __restrict__ Arows,
                                       const unsigned short* __restrict__ X,
                                       const unsigned short* __restrict__ Y,
                                       float cx, float cy, int m0, int n0,
                                       int t, SqSmem& sm) {
    const int lane = t & 63, w = t >> 6, quad = lane >> 4, l16 = lane & 15;
    const int wm = (w & 1) * 32, wn = (w >> 1) * 32;
    f32x4 acc[2][2];
#pragma unroll
    for (int i = 0; i < 2; ++i)
#pragma unroll
        for (int j = 0; j < 2; ++j) acc[i][j] = (f32x4){0.f, 0.f, 0.f, 0.f};
    for (int kt = 0; kt < 8; ++kt) {
        stage64(Arows, sm.s.A, m0, kt, t);
#pragma unroll
        for (int c = 0; c < 2; ++c) {
            int idx = c * 256 + t, row = idx >> 3, cc = idx & 7;
            int ccs = cc ^ (row & 7);
            size_t ga = (size_t)(n0 + row) * 512 + kt * 64 + cc * 8;
            us8 xv = *(const us8*)&X[ga];
            us8 yv = *(const us8*)&Y[ga];
            us8 g;
#pragma unroll
            for (int j = 0; j < 8; ++j)
                g[j] = f2bf(cx * bf2f(xv[j]) + cy * bf2f(yv[j]));
            *(us8*)&sm.s.B[row * 64 + ccs * 8] = g;
        }
        __syncthreads();
        MFMA_STEP(acc)
        __syncthreads();
    }
    ACC_TO_EPI(acc)
}

// gemm64_f32src: 64x64 tile of Arows·Bsrc (BOTH fp32 row-major, stride 512),
// staged with inline f2bf; B transposed via scalar scatter (r5/r7-proven).
// Only used for A^2 (64 blocks).
__device__ inline void gemm64_f32src(const float* __restrict__ Arows,
                                     const float* __restrict__ Bsrc,
                                     int m0, int n0, int t, SqSmem& sm) {
    const int lane = t & 63, w = t >> 6, quad = lane >> 4, l16 = lane & 15;
    const int wm = (w & 1) * 32, wn = (w >> 1) * 32;
    const int r = t >> 2, cq = t & 3;
    f32x4 acc[2][2];
#pragma unroll
    for (int i = 0; i < 2; ++i)
#pragma unroll
        for (int j = 0; j < 2; ++j) acc[i][j] = (f32x4){0.f, 0.f, 0.f, 0.f};
    for (int kt = 0; kt < 8; ++kt) {
        float va[16];
#pragma unroll
        for (int u = 0; u < 4; ++u) {
            float4 f = *(const float4*)&Arows[(size_t)(m0 + r) * 512 + kt * 64 + cq * 16 + u * 4];
            va[u * 4 + 0] = f.x; va[u * 4 + 1] = f.y;
            va[u * 4 + 2] = f.z; va[u * 4 + 3] = f.w;
        }
#pragma unroll
        for (int j2 = 0; j2 < 2; ++j2) {
            us8 h;
#pragma unroll
            for (int j = 0; j < 8; ++j) h[j] = f2bf(va[j2 * 8 + j]);
            int cc = cq * 2 + j2;
            *(us8*)&sm.s.A[r * 64 + (cc ^ (r & 7)) * 8] = h;
        }
#pragma unroll
        for (int u = 0; u < 4; ++u) {
            float4 f = *(const float4*)&Bsrc[(size_t)(kt * 64 + r) * 512 + n0 + cq * 16 + u * 4];
            float vv[4] = {f.x, f.y, f.z, f.w};
#pragma unroll
            for (int j = 0; j < 4; ++j) {
                int n = cq * 16 + u * 4 + j;
                sm.s.B[n * 64 + ((r >> 3) ^ (n & 7)) * 8 + (r & 7)] = f2bf(vv[j]);
            }
        }
        __syncthreads();
        MFMA_STEP(acc)
        __syncthreads();
    }
    ACC_TO_EPI(acc)
}

__device__ inline void epi_out_bf(unsigned short* __restrict__ dst, int m0,
                                  int n0, int t, SqSmem& sm) {
    const int r = t >> 2, cq = t & 3;
    us8 h0, h1;
#pragma unroll
    for (int j = 0; j < 8; ++j) {
        h0[j] = f2bf(sm.epi[r * 68 + cq * 16 + j]);
        h1[j] = f2bf(sm.epi[r * 68 + cq * 16 + 8 + j]);
    }
    *(us8*)&dst[(size_t)(m0 + r) * 512 + n0 + cq * 16]     = h0;
    *(us8*)&dst[(size_t)(m0 + r) * 512 + n0 + cq * 16 + 8] = h1;
}
__device__ inline void epi_out_bfT(unsigned short* __restrict__ dst, int m0,
                                   int n0, int t, SqSmem& sm) {
    const int cf = t >> 2, rq = t & 3;
    us8 o0, o1;
#pragma unroll
    for (int i = 0; i < 8; ++i) {
        o0[i] = f2bf(sm.epi[(rq * 16 + i) * 68 + cf]);
        o1[i] = f2bf(sm.epi[(rq * 16 + 8 + i) * 68 + cf]);
    }
    *(us8*)&dst[(size_t)(n0 + cf) * 512 + m0 + rq * 16]     = o0;
    *(us8*)&dst[(size_t)(n0 + cf) * 512 + m0 + rq * 16 + 8] = o1;
}

// ===========================================================================
// prep (persistent, grid 256 = 1 block/CU, 4 phases, 3 grid barriers):
//  P1: b<64: A2 = f32src(A,A) -> A2_bf,A2T_bf; b<128: AT_bf transpose;
//      b>=128: conversions (x_bf 8/thr, W1_bf 4/thr, A_bf 1/thr, y=b2)
//  P2: b<64:  GT  = A2^T·(c3A+c4A2)^T = (c3A3+c4A4)^T   [combineB]
//      b<128: A4T = A2^T·A2^T = (A4)^T                   [gemm64_mfma]
//  P3: b<64:  HT  = A4^T·(c5A+c6A2)^T = (c5A5+c6A6)^T; epilogue assembles
//             Q'T = AT + c2·A2T + GT + HT  -> QpT_bf
//  P4: all 256: w1f = W1 + W1_bf·Q'  (= W1·(I+A+c2A2+...+c6A6))
// ===========================================================================
__global__ __launch_bounds__(256) void prep(
    const float* __restrict__ A, const float* __restrict__ x,
    const float* __restrict__ W1, const float* __restrict__ b2,
    unsigned short* __restrict__ A2_bf, unsigned short* __restrict__ A2T_bf,
    unsigned short* __restrict__ AT_bf, unsigned short* __restrict__ A_bf,
    unsigned short* __restrict__ A4T_bf, unsigned short* __restrict__ GT_bf,
    unsigned short* __restrict__ QpT_bf, unsigned short* __restrict__ x_bf,
    unsigned short* __restrict__ W1_bf, unsigned short* __restrict__ w1f,
    float* __restrict__ y, unsigned* __restrict__ cnt) {
    __shared__ SqSmem sm;
    const int b = blockIdx.x, t = threadIdx.x;

    // ---------------- P1 ----------------
    if (b < 64) {
        const int m0 = (b >> 3) * 64, n0 = (b & 7) * 64;
        gemm64_f32src(A, A, m0, n0, t, sm);
        epi_out_bf(A2_bf, m0, n0, t, sm);
        epi_out_bfT(A2T_bf, m0, n0, t, sm);
    } else if (b < 128) {
        const int bb = b - 64, m0 = (bb >> 3) * 64, n0 = (bb & 7) * 64;
        const int r = t >> 2, cq = t & 3;
#pragma unroll
        for (int u = 0; u < 4; ++u) {
            float4 f = *(const float4*)&A[(size_t)(m0 + r) * 512 + n0 + cq * 16 + u * 4];
            sm.epi[r * 68 + cq * 16 + u * 4 + 0] = f.x;
            sm.epi[r * 68 + cq * 16 + u * 4 + 1] = f.y;
            sm.epi[r * 68 + cq * 16 + u * 4 + 2] = f.z;
            sm.epi[r * 68 + cq * 16 + u * 4 + 3] = f.w;
        }
        __syncthreads();
        epi_out_bfT(AT_bf, m0, n0, t, sm);
    } else {
        const int gid = (b - 128) * 256 + t;     // 0 .. 32767
        const float4* x4 = (const float4*)x;
#pragma unroll
        for (int i = 0; i < 8; ++i) {            // x: 262144 chunks
            int id = gid + i * 32768;
            float4 v0 = x4[(size_t)id * 2], v1 = x4[(size_t)id * 2 + 1];
            us8 o;
            o[0] = f2bf(v0.x); o[1] = f2bf(v0.y); o[2] = f2bf(v0.z); o[3] = f2bf(v0.w);
            o[4] = f2bf(v1.x); o[5] = f2bf(v1.y); o[6] = f2bf(v1.z); o[7] = f2bf(v1.w);
            *(us8*)&x_bf[(size_t)id * 8] = o;
        }
        const float4* w4 = (const float4*)W1;
#pragma unroll
        for (int i = 0; i < 4; ++i) {            // W1: 131072 chunks
            int id = gid + i * 32768;
            float4 v0 = w4[(size_t)id * 2], v1 = w4[(size_t)id * 2 + 1];
            us8 o;
            o[0] = f2bf(v0.x); o[1] = f2bf(v0.y); o[2] = f2bf(v0.z); o[3] = f2bf(v0.w);
            o[4] = f2bf(v1.x); o[5] = f2bf(v1.y); o[6] = f2bf(v1.z); o[7] = f2bf(v1.w);
            *(us8*)&W1_bf[(size_t)id * 8] = o;
        }
        {                                        // A: 32768 chunks
            const float4* a4 = (const float4*)A;
            float4 v0 = a4[(size_t)gid * 2], v1 = a4[(size_t)gid * 2 + 1];
            us8 o;
            o[0] = f2bf(v0.x); o[1] = f2bf(v0.y); o[2] = f2bf(v0.z); o[3] = f2bf(v0.w);
            o[4] = f2bf(v1.x); o[5] = f2bf(v1.y); o[6] = f2bf(v1.z); o[7] = f2bf(v1.w);
            *(us8*)&A_bf[(size_t)gid * 8] = o;
        }
#pragma unroll
        for (int i = 0; i < 2; ++i) {            // y init: 40960 entries
            int id = gid + i * 32768;
            if (id < B_SZ * DY) y[id] = b2[id % 10];
        }
    }
    gridbar(cnt, 256);

    // ---------------- P2 ----------------
    if (b < 64) {
        const int m0 = (b >> 3) * 64, n0 = (b & 7) * 64;
        gemm64_combineB(A2T_bf, A_bf, A2_bf, C3, C4, m0, n0, t, sm);
        epi_out_bf(GT_bf, m0, n0, t, sm);
    } else if (b < 128) {
        const int bb = b - 64, m0 = (bb >> 3) * 64, n0 = (bb & 7) * 64;
        gemm64_mfma(A2T_bf, A2_bf, m0, n0, t, sm);   // A2^T·A2^T = A4^T
        epi_out_bf(A4T_bf, m0, n0, t, sm);
    }
    gridbar(cnt, 512);

    // ---------------- P3 ----------------
    if (b < 64) {
        const int m0 = (b >> 3) * 64, n0 = (b & 7) * 64;
        gemm64_combineB(A4T_bf, A_bf, A2_bf, C5, C6, m0, n0, t, sm);
        const int r = t >> 2, cq = t & 3;
        size_t gb = (size_t)(m0 + r) * 512 + n0 + cq * 16;
        us8 at0  = *(const us8*)&AT_bf[gb],  at1  = *(const us8*)&AT_bf[gb + 8];
        us8 a2t0 = *(const us8*)&A2T_bf[gb], a2t1 = *(const us8*)&A2T_bf[gb + 8];
        us8 gt0  = *(const us8*)&GT_bf[gb],  gt1  = *(const us8*)&GT_bf[gb + 8];
        us8 o0, o1;
#pragma unroll
        for (int j = 0; j < 8; ++j) {
            o0[j] = f2bf(bf2f(at0[j]) + C2 * bf2f(a2t0[j]) + bf2f(gt0[j]) +
                         sm.epi[r * 68 + cq * 16 + j]);
            o1[j] = f2bf(bf2f(at1[j]) + C2 * bf2f(a2t1[j]) + bf2f(gt1[j]) +
                         sm.epi[r * 68 + cq * 16 + 8 + j]);
        }
        *(us8*)&QpT_bf[gb]     = o0;
        *(us8*)&QpT_bf[gb + 8] = o1;
    }
    gridbar(cnt, 768);

    // ---------------- P4 ----------------
    {
        const int m0 = (b >> 3) * 64, n0 = (b & 7) * 64;
        gemm64_mfma(W1_bf, QpT_bf, m0, n0, t, sm);
        const int r = t >> 2, cq = t & 3;
        size_t gb = (size_t)(m0 + r) * 512 + n0 + cq * 16;
        float4 wa = *(const float4*)&W1[gb],     wbv = *(const float4*)&W1[gb + 4];
        float4 wc = *(const float4*)&W1[gb + 8], wd  = *(const float4*)&W1[gb + 12];
        float wf[16] = {wa.x, wa.y, wa.z, wa.w, wbv.x, wbv.y, wbv.z, wbv.w,
                        wc.x, wc.y, wc.z, wc.w, wd.x,  wd.y,  wd.z,  wd.w};
        us8 h0, h1;
#pragma unroll
        for (int j = 0; j < 8; ++j) {
            h0[j] = f2bf(wf[j]     + sm.epi[r * 68 + cq * 16 + j]);
            h1[j] = f2bf(wf[8 + j] + sm.epi[r * 68 + cq * 16 + 8 + j]);
        }
        *(us8*)&w1f[gb]     = h0;
        *(us8*)&w1f[gb + 8] = h1;
    }
}

// ===========================================================================
// mlp (unchanged r1, proven): 128x128 tiles, grid (32,16), gl16 staging,
// acc[4][4]/wave; epilogue bias+relu -> LDS h, h@W2^T MFMA, atomicAdd y.
// ===========================================================================
union SmemU {
    struct { unsigned short A[128 * 64]; unsigned short B[128 * 64]; } s; // 32 KB
    struct { unsigned short h[128 * 136]; } e;                            // 34.8 KB
};

__global__ __launch_bounds__(256) void mlp_kernel(
    const unsigned short* __restrict__ x_bf,
    const unsigned short* __restrict__ w1f,
    const float* __restrict__ b1, const float* __restrict__ W2,
    float* __restrict__ y) {
    __shared__ SmemU sm;
    const int t    = threadIdx.x;
    const int lane = t & 63, w = t >> 6;
    const int quad = lane >> 4, l16 = lane & 15;
    const int wm = (w & 1) * 64, wn = (w >> 1) * 64;
    const int m0g = blockIdx.x * 128, n0g = blockIdx.y * 128;

    f32x4 acc[4][4];
#pragma unroll
    for (int i = 0; i < 4; ++i)
#pragma unroll
        for (int j = 0; j < 4; ++j) acc[i][j] = (f32x4){0.f, 0.f, 0.f, 0.f};

    for (int kt = 0; kt < 8; ++kt) {
#pragma unroll
        for (int i = 0; i < 4; ++i) {
            int o = w * 256 + i * 64 + lane;
            int row = o >> 3, cc = (o & 7) ^ (row & 7);
            gl16(&x_bf[(size_t)(m0g + row) * 512 + kt * 64 + cc * 8],
                 &sm.s.A[(size_t)(w * 256 + i * 64) * 8]);
        }
#pragma unroll
        for (int i = 0; i < 4; ++i) {
            int o = w * 256 + i * 64 + lane;
            int row = o >> 3, cc = (o & 7) ^ (row & 7);
            gl16(&w1f[(size_t)(n0g + row) * 512 + kt * 64 + cc * 8],
                 &sm.s.B[(size_t)(w * 256 + i * 64) * 8]);
        }
        __syncthreads();
#pragma unroll
        for (int ks = 0; ks < 2; ++ks) {
            bf16x8 af[4], bfr[4];
#pragma unroll
            for (int i = 0; i < 4; ++i) {
                int ra = wm + i * 16 + l16, ca = (ks * 4 + quad) ^ (ra & 7);
                af[i] = *(const bf16x8*)&sm.s.A[ra * 64 + ca * 8];
                int rb = wn + i * 16 + l16, cb = (ks * 4 + quad) ^ (rb & 7);
                bfr[i] = *(const bf16x8*)&sm.s.B[rb * 64 + cb * 8];
            }
#pragma unroll
            for (int i = 0; i < 4; ++i)
#pragma unroll
                for (int j = 0; j < 4; ++j)
                    acc[i][j] = __builtin_amdgcn_mfma_f32_16x16x32_bf16(
                        af[i], bfr[j], acc[i][j], 0, 0, 0);
        }
        __syncthreads();
    }

    float bias[4];
#pragma unroll
    for (int j = 0; j < 4; ++j) bias[j] = b1[n0g + wn + j * 16 + l16];
#pragma unroll
    for (int i = 0; i < 4; ++i)
#pragma unroll
        for (int j = 0; j < 4; ++j)
#pragma unroll
            for (int r = 0; r < 4; ++r) {
                float h = acc[i][j][r] + bias[j];
                h = h > 0.f ? h : 0.f;
                sm.e.h[(wm + i * 16 + quad * 4 + r) * 136 + wn + j * 16 + l16] =
                    f2bf(h);
            }
    __syncthreads();

    {
        bf16x8 wfrag[4];
#pragma unroll
        for (int kc = 0; kc < 4; ++kc) {
            us8 wb;
            if (l16 < DY) {
                const float* wp = &W2[(size_t)l16 * H_SZ + n0g + kc * 32 + quad * 8];
#pragma unroll
                for (int j = 0; j < 8; ++j) wb[j] = f2bf(wp[j]);
            } else {
#pragma unroll
                for (int j = 0; j < 8; ++j) wb[j] = 0;
            }
            wfrag[kc] = *(bf16x8*)&wb;
        }
#pragma unroll
        for (int hh = 0; hh < 2; ++hh) {
            const int mrow = w * 32 + hh * 16;
            f32x4 ay = (f32x4){0.f, 0.f, 0.f, 0.f};
#pragma unroll
            for (int kc = 0; kc < 4; ++kc) {
                bf16x8 af = *(const bf16x8*)&sm.e.h[(mrow + l16) * 136 +
                                                    kc * 32 + quad * 8];
                ay = __builtin_amdgcn_mfma_f32_16x16x32_bf16(af, wfrag[kc], ay,
                                                             0, 0, 0);
            }
            if (l16 < DY) {
#pragma unroll
                for (int r = 0; r < 4; ++r)
                    atomicAdd(&y[(size_t)(m0g + mrow + quad * 4 + r) * DY + l16],
                              ay[r]);
            }
        }
    }
}

// ===========================================================================
extern "C" void kernel_launch(void* const* d_in, const int* in_sizes, int n_in,
                              void* d_out, int out_size, void* d_ws, size_t ws_size,
                              hipStream_t stream) {
    const float* x  = (const float*)d_in[0];
    const float* A  = (const float*)d_in[1];
    const float* W1 = (const float*)d_in[2];
    const float* b1 = (const float*)d_in[3];
    const float* W2 = (const float*)d_in[4];
    const float* b2 = (const float*)d_in[5];
    float* y = (float*)d_out;

    char* ws = (char*)d_ws;
    const size_t HMB = 512u * 1024, MB = 1u << 20;
    unsigned short* AT_bf  = (unsigned short*)(ws);                  // 512 KB
    unsigned short* A2_bf  = (unsigned short*)(ws + 1 * HMB);        // 512 KB
    unsigned short* A2T_bf = (unsigned short*)(ws + 2 * HMB);        // 512 KB
    unsigned short* A4T_bf = (unsigned short*)(ws + 3 * HMB);        // 512 KB
    unsigned short* A_bf   = (unsigned short*)(ws + 4 * HMB);        // 512 KB
    unsigned short* GT_bf  = (unsigned short*)(ws + 5 * HMB);        // 512 KB
    unsigned short* QpT_bf = (unsigned short*)(ws + 6 * HMB);        // 512 KB
    unsigned short* w1f    = (unsigned short*)(ws + 4 * MB);         // 2 MB
    unsigned short* W1_bf  = (unsigned short*)(ws + 6 * MB);         // 2 MB
    unsigned short* x_bf   = (unsigned short*)(ws + 8 * MB);         // 4 MB
    unsigned*       cnt    = (unsigned*)(ws + 12 * MB);              // 128 B

    hipMemsetAsync(cnt, 0, 128, stream);
    prep<<<256, 256, 0, stream>>>(A, x, W1, b2, A2_bf, A2T_bf, AT_bf, A_bf,
                                  A4T_bf, GT_bf, QpT_bf, x_bf, W1_bf, w1f, y,
                                  cnt);
    mlp_kernel<<<dim3(32, 16), dim3(256), 0, stream>>>(x_bf, w1f, b1, W2, y);
}

// Round 5
// 140.711 us; speedup vs baseline: 2.3190x; 2.3190x over previous
//
#include <hip/hip_runtime.h>
#include <hip/hip_bf16.h>

#define B_SZ 4096
#define DZ   512
#define H_SZ 2048
#define DY   10

// c_k = C(64,k)/64^k  (binomial coefficients of (1+u/64)^64), c0=c1=1
#define C2 0.4921875f
#define C3 0.158935546875f
#define C4 0.037872314453125f
#define C5 ((float)(7624512.0/1073741824.0))
#define C6 ((float)(74974368.0/68719476736.0))

typedef __attribute__((ext_vector_type(8))) __bf16 bf16x8;
typedef __attribute__((ext_vector_type(4))) float  f32x4;
typedef __attribute__((ext_vector_type(8))) unsigned short us8;

__device__ inline unsigned short f2bf(float f) {
    unsigned u = __float_as_uint(f);
    u += 0x7fffu + ((u >> 16) & 1u);   // RTNE
    return (unsigned short)(u >> 16);
}
__device__ inline float bf2f(unsigned short s) {
    return __uint_as_float(((unsigned)s) << 16);
}

// global -> LDS direct 16B copy. LDS dest is wave-uniform base + lane*16
// (HW semantics): callers pre-apply the inverse XOR swizzle on the per-lane
// GLOBAL address and keep the LDS side linear (rule #21 pattern).
// r4 lesson: cross-XCD phase handoff goes at KERNEL boundaries — in-kernel
// grid barriers cost ~70us each in device-scope L2 flush on MI355X.
__device__ __forceinline__ void gl16(const void* g, void* l) {
    __builtin_amdgcn_global_load_lds(
        (const __attribute__((address_space(1))) unsigned int*)(size_t)g,
        (__attribute__((address_space(3))) unsigned int*)(unsigned)(size_t)l,
        16, 0, 0);
}

// ===== 64x64 tile machinery (16 KB LDS) ====================================
union SqSmem {
    struct { unsigned short A[64 * 64]; unsigned short B[64 * 64]; } s; // 16 KB
    float epi[64 * 68];                                                 // 17.4 KB
};

// Stage a 64x64 bf16 tile into LDS layout lds[row*64 + (cc^(row&7))*8]
// via global_load_lds: linear LDS chunk o -> row=o>>3, src cc=(o&7)^(row&7).
__device__ __forceinline__ void stage64(const unsigned short* __restrict__ src,
                                        unsigned short* lds, int row_base,
                                        int kt, int t) {
    const int w = t >> 6, lane = t & 63;
#pragma unroll
    for (int i = 0; i < 2; ++i) {
        int o = w * 128 + i * 64 + lane;
        int row = o >> 3, cc = (o & 7) ^ (row & 7);
        gl16(&src[(size_t)(row_base + row) * 512 + kt * 64 + cc * 8],
             &lds[(size_t)(w * 128 + i * 64) * 8]);
    }
}

#define MFMA_STEP(acc)                                                        \
    {                                                                         \
        _Pragma("unroll")                                                     \
        for (int ks = 0; ks < 2; ++ks) {                                      \
            bf16x8 af[2], bfr[2];                                             \
            _Pragma("unroll")                                                 \
            for (int i = 0; i < 2; ++i) {                                     \
                int ra = wm + i * 16 + l16, ca = (ks * 4 + quad) ^ (ra & 7);  \
                af[i] = *(const bf16x8*)&sm.s.A[ra * 64 + ca * 8];            \
                int rb = wn + i * 16 + l16, cb = (ks * 4 + quad) ^ (rb & 7);  \
                bfr[i] = *(const bf16x8*)&sm.s.B[rb * 64 + cb * 8];           \
            }                                                                 \
            _Pragma("unroll")                                                 \
            for (int i = 0; i < 2; ++i)                                       \
                _Pragma("unroll")                                             \
                for (int j = 0; j < 2; ++j)                                   \
                    acc[i][j] = __builtin_amdgcn_mfma_f32_16x16x32_bf16(      \
                        af[i], bfr[j], acc[i][j], 0, 0, 0);                   \
        }                                                                     \
    }

#define ACC_TO_EPI(acc)                                                       \
    {                                                                         \
        _Pragma("unroll")                                                     \
        for (int i = 0; i < 2; ++i)                                           \
            _Pragma("unroll")                                                 \
            for (int j = 0; j < 2; ++j)                                       \
                _Pragma("unroll")                                             \
                for (int rr = 0; rr < 4; ++rr)                                \
                    sm.epi[(wm + i * 16 + quad * 4 + rr) * 68 +               \
                           wn + j * 16 + l16] = acc[i][j][rr];                \
        __syncthreads();                                                      \
    }

// gemm64_mfma: 64x64 tile of (Arows)·(Brows)^T, bf16 sources, K=512 -> sm.epi
__device__ inline void gemm64_mfma(const unsigned short* __restrict__ Arows,
                                   const unsigned short* __restrict__ Brows,
                                   int m0, int n0, int t, SqSmem& sm) {
    const int lane = t & 63, w = t >> 6, quad = lane >> 4, l16 = lane & 15;
    const int wm = (w & 1) * 32, wn = (w >> 1) * 32;
    f32x4 acc[2][2];
#pragma unroll
    for (int i = 0; i < 2; ++i)
#pragma unroll
        for (int j = 0; j < 2; ++j) acc[i][j] = (f32x4){0.f, 0.f, 0.f, 0.f};
    for (int kt = 0; kt < 8; ++kt) {
        stage64(Arows, sm.s.A, m0, kt, t);
        stage64(Brows, sm.s.B, n0, kt, t);
        __syncthreads();
        MFMA_STEP(acc)
        __syncthreads();
    }
    ACC_TO_EPI(acc)
}

// gemm64_f32src: 64x64 tile of Arows·Bsrc (BOTH fp32 row-major, stride 512),
// staged with inline f2bf; B transposed via scalar scatter. Only A^2 uses
// this (64 blocks) — the r1->r5 change removed 256 scatter blocks.
__device__ inline void gemm64_f32src(const float* __restrict__ Arows,
                                     const float* __restrict__ Bsrc,
                                     int m0, int n0, int t, SqSmem& sm) {
    const int lane = t & 63, w = t >> 6, quad = lane >> 4, l16 = lane & 15;
    const int wm = (w & 1) * 32, wn = (w >> 1) * 32;
    const int r = t >> 2, cq = t & 3;
    f32x4 acc[2][2];
#pragma unroll
    for (int i = 0; i < 2; ++i)
#pragma unroll
        for (int j = 0; j < 2; ++j) acc[i][j] = (f32x4){0.f, 0.f, 0.f, 0.f};
    for (int kt = 0; kt < 8; ++kt) {
        float va[16];
#pragma unroll
        for (int u = 0; u < 4; ++u) {
            float4 f = *(const float4*)&Arows[(size_t)(m0 + r) * 512 + kt * 64 + cq * 16 + u * 4];
            va[u * 4 + 0] = f.x; va[u * 4 + 1] = f.y;
            va[u * 4 + 2] = f.z; va[u * 4 + 3] = f.w;
        }
#pragma unroll
        for (int j2 = 0; j2 < 2; ++j2) {
            us8 h;
#pragma unroll
            for (int j = 0; j < 8; ++j) h[j] = f2bf(va[j2 * 8 + j]);
            int cc = cq * 2 + j2;
            *(us8*)&sm.s.A[r * 64 + (cc ^ (r & 7)) * 8] = h;
        }
#pragma unroll
        for (int u = 0; u < 4; ++u) {
            float4 f = *(const float4*)&Bsrc[(size_t)(kt * 64 + r) * 512 + n0 + cq * 16 + u * 4];
            float vv[4] = {f.x, f.y, f.z, f.w};
#pragma unroll
            for (int j = 0; j < 4; ++j) {
                int n = cq * 16 + u * 4 + j;
                sm.s.B[n * 64 + ((r >> 3) ^ (n & 7)) * 8 + (r & 7)] = f2bf(vv[j]);
            }
        }
        __syncthreads();
        MFMA_STEP(acc)
        __syncthreads();
    }
    ACC_TO_EPI(acc)
}

__device__ inline void epi_out_bf(unsigned short* __restrict__ dst, int m0,
                                  int n0, int t, SqSmem& sm) {
    const int r = t >> 2, cq = t & 3;
    us8 h0, h1;
#pragma unroll
    for (int j = 0; j < 8; ++j) {
        h0[j] = f2bf(sm.epi[r * 68 + cq * 16 + j]);
        h1[j] = f2bf(sm.epi[r * 68 + cq * 16 + 8 + j]);
    }
    *(us8*)&dst[(size_t)(m0 + r) * 512 + n0 + cq * 16]     = h0;
    *(us8*)&dst[(size_t)(m0 + r) * 512 + n0 + cq * 16 + 8] = h1;
}
__device__ inline void epi_out_bfT(unsigned short* __restrict__ dst, int m0,
                                   int n0, int t, SqSmem& sm) {
    const int cf = t >> 2, rq = t & 3;
    us8 o0, o1;
#pragma unroll
    for (int i = 0; i < 8; ++i) {
        o0[i] = f2bf(sm.epi[(rq * 16 + i) * 68 + cf]);
        o1[i] = f2bf(sm.epi[(rq * 16 + 8 + i) * 68 + cf]);
    }
    *(us8*)&dst[(size_t)(n0 + cf) * 512 + m0 + rq * 16]     = o0;
    *(us8*)&dst[(size_t)(n0 + cf) * 512 + m0 + rq * 16 + 8] = o1;
}

// ===========================================================================
// k_s1 (grid 256): b<64: A2 = f32src(A,A) -> A2_bf,A2T_bf (only remaining
// f32-scatter path); b<128: AT_bf transpose; b>=128: conversions
// (x_bf 8/thr, W1_bf 4/thr, y=b2).
// ===========================================================================
__global__ __launch_bounds__(256) void k_s1(
    const float* __restrict__ A, const float* __restrict__ x,
    const float* __restrict__ W1, const float* __restrict__ b2,
    unsigned short* __restrict__ A2_bf, unsigned short* __restrict__ A2T_bf,
    unsigned short* __restrict__ AT_bf, unsigned short* __restrict__ x_bf,
    unsigned short* __restrict__ W1_bf, float* __restrict__ y) {
    __shared__ SqSmem sm;
    const int b = blockIdx.x, t = threadIdx.x;

    if (b < 64) {
        const int m0 = (b >> 3) * 64, n0 = (b & 7) * 64;
        gemm64_f32src(A, A, m0, n0, t, sm);
        epi_out_bf(A2_bf, m0, n0, t, sm);
        epi_out_bfT(A2T_bf, m0, n0, t, sm);
    } else if (b < 128) {
        const int bb = b - 64, m0 = (bb >> 3) * 64, n0 = (bb & 7) * 64;
        const int r = t >> 2, cq = t & 3;
#pragma unroll
        for (int u = 0; u < 4; ++u) {
            float4 f = *(const float4*)&A[(size_t)(m0 + r) * 512 + n0 + cq * 16 + u * 4];
            sm.epi[r * 68 + cq * 16 + u * 4 + 0] = f.x;
            sm.epi[r * 68 + cq * 16 + u * 4 + 1] = f.y;
            sm.epi[r * 68 + cq * 16 + u * 4 + 2] = f.z;
            sm.epi[r * 68 + cq * 16 + u * 4 + 3] = f.w;
        }
        __syncthreads();
        epi_out_bfT(AT_bf, m0, n0, t, sm);
    } else {
        const int gid = (b - 128) * 256 + t;     // 0 .. 32767
        const float4* x4 = (const float4*)x;
#pragma unroll
        for (int i = 0; i < 8; ++i) {            // x: 262144 chunks
            int id = gid + i * 32768;
            float4 v0 = x4[(size_t)id * 2], v1 = x4[(size_t)id * 2 + 1];
            us8 o;
            o[0] = f2bf(v0.x); o[1] = f2bf(v0.y); o[2] = f2bf(v0.z); o[3] = f2bf(v0.w);
            o[4] = f2bf(v1.x); o[5] = f2bf(v1.y); o[6] = f2bf(v1.z); o[7] = f2bf(v1.w);
            *(us8*)&x_bf[(size_t)id * 8] = o;
        }
        const float4* w4 = (const float4*)W1;
#pragma unroll
        for (int i = 0; i < 4; ++i) {            // W1: 131072 chunks
            int id = gid + i * 32768;
            float4 v0 = w4[(size_t)id * 2], v1 = w4[(size_t)id * 2 + 1];
            us8 o;
            o[0] = f2bf(v0.x); o[1] = f2bf(v0.y); o[2] = f2bf(v0.z); o[3] = f2bf(v0.w);
            o[4] = f2bf(v1.x); o[5] = f2bf(v1.y); o[6] = f2bf(v1.z); o[7] = f2bf(v1.w);
            *(us8*)&W1_bf[(size_t)id * 8] = o;
        }
#pragma unroll
        for (int i = 0; i < 2; ++i) {            // y init: 40960 entries
            int id = gid + i * 32768;
            if (id < B_SZ * DY) y[id] = b2[id % 10];
        }
    }
}

// ===========================================================================
// k_s2 (grid 576, all pure-bf16 gl16 staging; no dependencies among parts):
//   b<64  : A4T = A2^T·(A2)^T = (A2·A2)^T   [r4-proven math]
//   b<320 : U1  = W1·A  = W1_bf·(AT)^T
//   else  : U2  = W1·A2 = W1_bf·(A2T)^T
// ===========================================================================
__global__ __launch_bounds__(256) void k_s2(
    const unsigned short* __restrict__ W1_bf,
    const unsigned short* __restrict__ A2_bf,
    const unsigned short* __restrict__ A2T_bf,
    const unsigned short* __restrict__ AT_bf,
    unsigned short* __restrict__ A4T_bf, unsigned short* __restrict__ U1_bf,
    unsigned short* __restrict__ U2_bf) {
    __shared__ SqSmem sm;
    const int b = blockIdx.x, t = threadIdx.x;
    if (b < 64) {
        const int m0 = (b >> 3) * 64, n0 = (b & 7) * 64;
        gemm64_mfma(A2T_bf, A2_bf, m0, n0, t, sm);   // A2^T·A2^T = A4^T
        epi_out_bf(A4T_bf, m0, n0, t, sm);
    } else if (b < 320) {
        const int bb = b - 64, m0 = (bb >> 3) * 64, n0 = (bb & 7) * 64;
        gemm64_mfma(W1_bf, AT_bf, m0, n0, t, sm);    // U1 = W1·A
        epi_out_bf(U1_bf, m0, n0, t, sm);
    } else {
        const int bb = b - 320, m0 = (bb >> 3) * 64, n0 = (bb & 7) * 64;
        gemm64_mfma(W1_bf, A2T_bf, m0, n0, t, sm);   // U2 = W1·A2
        epi_out_bf(U2_bf, m0, n0, t, sm);
    }
}

// ===========================================================================
// k_s3 (grid 256, two accumulated K-passes = K=1024):
//   acc  = (c3·U1 + c4·U2)·A2 + (c5·U1 + c6·U2)·A4
//   w1f  = W1 + U1 + c2·U2 + acc
//        = W1·(I + A + c2A² + c3A³ + c4A⁴ + c5A⁵ + c6A⁶)
// A-side: reg-combine + swizzled ds_write (r3-proven); B-side: gl16.
// ===========================================================================
__global__ __launch_bounds__(256) void k_s3(
    const float* __restrict__ W1, const unsigned short* __restrict__ U1_bf,
    const unsigned short* __restrict__ U2_bf,
    const unsigned short* __restrict__ A2T_bf,
    const unsigned short* __restrict__ A4T_bf,
    unsigned short* __restrict__ w1f) {
    __shared__ SqSmem sm;
    const int b = blockIdx.x, t = threadIdx.x;
    const int m0 = (b >> 3) * 64, n0 = (b & 7) * 64;
    const int lane = t & 63, w = t >> 6, quad = lane >> 4, l16 = lane & 15;
    const int wm = (w & 1) * 32, wn = (w >> 1) * 32;
    f32x4 acc[2][2];
#pragma unroll
    for (int i = 0; i < 2; ++i)
#pragma unroll
        for (int j = 0; j < 2; ++j) acc[i][j] = (f32x4){0.f, 0.f, 0.f, 0.f};

#pragma unroll
    for (int pass = 0; pass < 2; ++pass) {
        const unsigned short* __restrict__ Bt = pass ? A4T_bf : A2T_bf;
        const float c1c = pass ? C5 : C3;
        const float c2c = pass ? C6 : C4;
        for (int kt = 0; kt < 8; ++kt) {
            stage64(Bt, sm.s.B, n0, kt, t);
#pragma unroll
            for (int c = 0; c < 2; ++c) {
                int idx = c * 256 + t, row = idx >> 3, cc = idx & 7;
                int ccs = cc ^ (row & 7);
                size_t ga = (size_t)(m0 + row) * 512 + kt * 64 + cc * 8;
                us8 u1 = *(const us8*)&U1_bf[ga];
                us8 u2 = *(const us8*)&U2_bf[ga];
                us8 g;
#pragma unroll
                for (int j = 0; j < 8; ++j)
                    g[j] = f2bf(c1c * bf2f(u1[j]) + c2c * bf2f(u2[j]));
                *(us8*)&sm.s.A[row * 64 + ccs * 8] = g;
            }
            __syncthreads();
            MFMA_STEP(acc)
            __syncthreads();
        }
    }
    ACC_TO_EPI(acc)

    const int r = t >> 2, cq = t & 3;
    size_t gbase = (size_t)(m0 + r) * 512 + n0 + cq * 16;
    us8 u1a = *(const us8*)&U1_bf[gbase], u1b = *(const us8*)&U1_bf[gbase + 8];
    us8 u2a = *(const us8*)&U2_bf[gbase], u2b = *(const us8*)&U2_bf[gbase + 8];
    float4 wa = *(const float4*)&W1[gbase],      wbv = *(const float4*)&W1[gbase + 4];
    float4 wc = *(const float4*)&W1[gbase + 8],  wd  = *(const float4*)&W1[gbase + 12];
    float wf[16] = {wa.x, wa.y, wa.z, wa.w, wbv.x, wbv.y, wbv.z, wbv.w,
                    wc.x, wc.y, wc.z, wc.w, wd.x,  wd.y,  wd.z,  wd.w};
    us8 h0, h1;
#pragma unroll
    for (int j = 0; j < 8; ++j) {
        h0[j] = f2bf(wf[j] + bf2f(u1a[j]) + C2 * bf2f(u2a[j]) +
                     sm.epi[r * 68 + cq * 16 + j]);
        h1[j] = f2bf(wf[8 + j] + bf2f(u1b[j]) + C2 * bf2f(u2b[j]) +
                     sm.epi[r * 68 + cq * 16 + 8 + j]);
    }
    *(us8*)&w1f[gbase]     = h0;
    *(us8*)&w1f[gbase + 8] = h1;
}

// ===========================================================================
// mlp (unchanged r1, proven): 128x128 tiles, grid (32,16), gl16 staging,
// acc[4][4]/wave; epilogue bias+relu -> LDS h, h@W2^T MFMA, atomicAdd y.
// ===========================================================================
union SmemU {
    struct { unsigned short A[128 * 64]; unsigned short B[128 * 64]; } s; // 32 KB
    struct { unsigned short h[128 * 136]; } e;                            // 34.8 KB
};

__global__ __launch_bounds__(256) void mlp_kernel(
    const unsigned short* __restrict__ x_bf,
    const unsigned short* __restrict__ w1f,
    const float* __restrict__ b1, const float* __restrict__ W2,
    float* __restrict__ y) {
    __shared__ SmemU sm;
    const int t    = threadIdx.x;
    const int lane = t & 63, w = t >> 6;
    const int quad = lane >> 4, l16 = lane & 15;
    const int wm = (w & 1) * 64, wn = (w >> 1) * 64;
    const int m0g = blockIdx.x * 128, n0g = blockIdx.y * 128;

    f32x4 acc[4][4];
#pragma unroll
    for (int i = 0; i < 4; ++i)
#pragma unroll
        for (int j = 0; j < 4; ++j) acc[i][j] = (f32x4){0.f, 0.f, 0.f, 0.f};

    for (int kt = 0; kt < 8; ++kt) {
#pragma unroll
        for (int i = 0; i < 4; ++i) {
            int o = w * 256 + i * 64 + lane;
            int row = o >> 3, cc = (o & 7) ^ (row & 7);
            gl16(&x_bf[(size_t)(m0g + row) * 512 + kt * 64 + cc * 8],
                 &sm.s.A[(size_t)(w * 256 + i * 64) * 8]);
        }
#pragma unroll
        for (int i = 0; i < 4; ++i) {
            int o = w * 256 + i * 64 + lane;
            int row = o >> 3, cc = (o & 7) ^ (row & 7);
            gl16(&w1f[(size_t)(n0g + row) * 512 + kt * 64 + cc * 8],
                 &sm.s.B[(size_t)(w * 256 + i * 64) * 8]);
        }
        __syncthreads();
#pragma unroll
        for (int ks = 0; ks < 2; ++ks) {
            bf16x8 af[4], bfr[4];
#pragma unroll
            for (int i = 0; i < 4; ++i) {
                int ra = wm + i * 16 + l16, ca = (ks * 4 + quad) ^ (ra & 7);
                af[i] = *(const bf16x8*)&sm.s.A[ra * 64 + ca * 8];
                int rb = wn + i * 16 + l16, cb = (ks * 4 + quad) ^ (rb & 7);
                bfr[i] = *(const bf16x8*)&sm.s.B[rb * 64 + cb * 8];
            }
#pragma unroll
            for (int i = 0; i < 4; ++i)
#pragma unroll
                for (int j = 0; j < 4; ++j)
                    acc[i][j] = __builtin_amdgcn_mfma_f32_16x16x32_bf16(
                        af[i], bfr[j], acc[i][j], 0, 0, 0);
        }
        __syncthreads();
    }

    float bias[4];
#pragma unroll
    for (int j = 0; j < 4; ++j) bias[j] = b1[n0g + wn + j * 16 + l16];
#pragma unroll
    for (int i = 0; i < 4; ++i)
#pragma unroll
        for (int j = 0; j < 4; ++j)
#pragma unroll
            for (int r = 0; r < 4; ++r) {
                float h = acc[i][j][r] + bias[j];
                h = h > 0.f ? h : 0.f;
                sm.e.h[(wm + i * 16 + quad * 4 + r) * 136 + wn + j * 16 + l16] =
                    f2bf(h);
            }
    __syncthreads();

    {
        bf16x8 wfrag[4];
#pragma unroll
        for (int kc = 0; kc < 4; ++kc) {
            us8 wb;
            if (l16 < DY) {
                const float* wp = &W2[(size_t)l16 * H_SZ + n0g + kc * 32 + quad * 8];
#pragma unroll
                for (int j = 0; j < 8; ++j) wb[j] = f2bf(wp[j]);
            } else {
#pragma unroll
                for (int j = 0; j < 8; ++j) wb[j] = 0;
            }
            wfrag[kc] = *(bf16x8*)&wb;
        }
#pragma unroll
        for (int hh = 0; hh < 2; ++hh) {
            const int mrow = w * 32 + hh * 16;
            f32x4 ay = (f32x4){0.f, 0.f, 0.f, 0.f};
#pragma unroll
            for (int kc = 0; kc < 4; ++kc) {
                bf16x8 af = *(const bf16x8*)&sm.e.h[(mrow + l16) * 136 +
                                                    kc * 32 + quad * 8];
                ay = __builtin_amdgcn_mfma_f32_16x16x32_bf16(af, wfrag[kc], ay,
                                                             0, 0, 0);
            }
            if (l16 < DY) {
#pragma unroll
                for (int r = 0; r < 4; ++r)
                    atomicAdd(&y[(size_t)(m0g + mrow + quad * 4 + r) * DY + l16],
                              ay[r]);
            }
        }
    }
}

// ===========================================================================
extern "C" void kernel_launch(void* const* d_in, const int* in_sizes, int n_in,
                              void* d_out, int out_size, void* d_ws, size_t ws_size,
                              hipStream_t stream) {
    const float* x  = (const float*)d_in[0];
    const float* A  = (const float*)d_in[1];
    const float* W1 = (const float*)d_in[2];
    const float* b1 = (const float*)d_in[3];
    const float* W2 = (const float*)d_in[4];
    const float* b2 = (const float*)d_in[5];
    float* y = (float*)d_out;

    char* ws = (char*)d_ws;
    const size_t HMB = 512u * 1024, MB = 1u << 20;
    unsigned short* AT_bf  = (unsigned short*)(ws);                  // 512 KB
    unsigned short* A2_bf  = (unsigned short*)(ws + 1 * HMB);        // 512 KB
    unsigned short* A2T_bf = (unsigned short*)(ws + 2 * HMB);        // 512 KB
    unsigned short* A4T_bf = (unsigned short*)(ws + 3 * HMB);        // 512 KB
    unsigned short* U1_bf  = (unsigned short*)(ws + 2 * MB);         // 2 MB
    unsigned short* U2_bf  = (unsigned short*)(ws + 4 * MB);         // 2 MB
    unsigned short* w1f    = (unsigned short*)(ws + 6 * MB);         // 2 MB
    unsigned short* W1_bf  = (unsigned short*)(ws + 8 * MB);         // 2 MB
    unsigned short* x_bf   = (unsigned short*)(ws + 10 * MB);        // 4 MB

    k_s1<<<256, 256, 0, stream>>>(A, x, W1, b2, A2_bf, A2T_bf, AT_bf, x_bf,
                                  W1_bf, y);
    k_s2<<<576, 256, 0, stream>>>(W1_bf, A2_bf, A2T_bf, AT_bf, A4T_bf, U1_bf,
                                  U2_bf);
    k_s3<<<256, 256, 0, stream>>>(W1, U1_bf, U2_bf, A2T_bf, A4T_bf, w1f);
    mlp_kernel<<<dim3(32, 16), dim3(256), 0, stream>>>(x_bf, w1f, b1, W2, y);
}

// Round 6
// 133.586 us; speedup vs baseline: 2.4427x; 1.0533x over previous
//
#include <hip/hip_runtime.h>
#include <hip/hip_bf16.h>

#define B_SZ 4096
#define DZ   512
#define H_SZ 2048
#define DY   10

// c_k = C(64,k)/64^k  (binomial coefficients of (1+u/64)^64), c0=c1=1
#define C2 0.4921875f
#define C3 0.158935546875f
#define C4 0.037872314453125f
#define C5 ((float)(7624512.0/1073741824.0))
#define C6 ((float)(74974368.0/68719476736.0))

typedef __attribute__((ext_vector_type(8))) __bf16 bf16x8;
typedef __attribute__((ext_vector_type(4))) float  f32x4;
typedef __attribute__((ext_vector_type(8))) unsigned short us8;

__device__ inline unsigned short f2bf(float f) {
    unsigned u = __float_as_uint(f);
    u += 0x7fffu + ((u >> 16) & 1u);   // RTNE
    return (unsigned short)(u >> 16);
}
__device__ inline float bf2f(unsigned short s) {
    return __uint_as_float(((unsigned)s) << 16);
}

// global -> LDS direct 16B copy. LDS dest is wave-uniform base + lane*16
// (HW semantics): callers pre-apply the inverse XOR swizzle on the per-lane
// GLOBAL address and keep the LDS side linear (rule #21 pattern).
// r4 lesson: cross-XCD phase handoff goes at KERNEL boundaries — in-kernel
// grid barriers cost ~70us each in device-scope L2 flush on MI355X.
__device__ __forceinline__ void gl16(const void* g, void* l) {
    __builtin_amdgcn_global_load_lds(
        (const __attribute__((address_space(1))) unsigned int*)(size_t)g,
        (__attribute__((address_space(3))) unsigned int*)(unsigned)(size_t)l,
        16, 0, 0);
}

// ===== 64x64 tile machinery (16 KB LDS) ====================================
union SqSmem {
    struct { unsigned short A[64 * 64]; unsigned short B[64 * 64]; } s; // 16 KB
    float epi[64 * 68];                                                 // 17.4 KB
};

// Stage a 64x64 bf16 tile into LDS layout lds[row*64 + (cc^(row&7))*8]
// via global_load_lds: linear LDS chunk o -> row=o>>3, src cc=(o&7)^(row&7).
__device__ __forceinline__ void stage64(const unsigned short* __restrict__ src,
                                        unsigned short* lds, int row_base,
                                        int kt, int t) {
    const int w = t >> 6, lane = t & 63;
#pragma unroll
    for (int i = 0; i < 2; ++i) {
        int o = w * 128 + i * 64 + lane;
        int row = o >> 3, cc = (o & 7) ^ (row & 7);
        gl16(&src[(size_t)(row_base + row) * 512 + kt * 64 + cc * 8],
             &lds[(size_t)(w * 128 + i * 64) * 8]);
    }
}

#define MFMA_STEP(acc)                                                        \
    {                                                                         \
        _Pragma("unroll")                                                     \
        for (int ks = 0; ks < 2; ++ks) {                                      \
            bf16x8 af[2], bfr[2];                                             \
            _Pragma("unroll")                                                 \
            for (int i = 0; i < 2; ++i) {                                     \
                int ra = wm + i * 16 + l16, ca = (ks * 4 + quad) ^ (ra & 7);  \
                af[i] = *(const bf16x8*)&sm.s.A[ra * 64 + ca * 8];            \
                int rb = wn + i * 16 + l16, cb = (ks * 4 + quad) ^ (rb & 7);  \
                bfr[i] = *(const bf16x8*)&sm.s.B[rb * 64 + cb * 8];           \
            }                                                                 \
            _Pragma("unroll")                                                 \
            for (int i = 0; i < 2; ++i)                                       \
                _Pragma("unroll")                                             \
                for (int j = 0; j < 2; ++j)                                   \
                    acc[i][j] = __builtin_amdgcn_mfma_f32_16x16x32_bf16(      \
                        af[i], bfr[j], acc[i][j], 0, 0, 0);                   \
        }                                                                     \
    }

#define ACC_TO_EPI(acc)                                                       \
    {                                                                         \
        _Pragma("unroll")                                                     \
        for (int i = 0; i < 2; ++i)                                           \
            _Pragma("unroll")                                                 \
            for (int j = 0; j < 2; ++j)                                       \
                _Pragma("unroll")                                             \
                for (int rr = 0; rr < 4; ++rr)                                \
                    sm.epi[(wm + i * 16 + quad * 4 + rr) * 68 +               \
                           wn + j * 16 + l16] = acc[i][j][rr];                \
        __syncthreads();                                                      \
    }

// gemm64_mfma: 64x64 tile of (Arows)·(Brows)^T, bf16 sources, K=512 -> sm.epi
__device__ inline void gemm64_mfma(const unsigned short* __restrict__ Arows,
                                   const unsigned short* __restrict__ Brows,
                                   int m0, int n0, int t, SqSmem& sm) {
    const int lane = t & 63, w = t >> 6, quad = lane >> 4, l16 = lane & 15;
    const int wm = (w & 1) * 32, wn = (w >> 1) * 32;
    f32x4 acc[2][2];
#pragma unroll
    for (int i = 0; i < 2; ++i)
#pragma unroll
        for (int j = 0; j < 2; ++j) acc[i][j] = (f32x4){0.f, 0.f, 0.f, 0.f};
    for (int kt = 0; kt < 8; ++kt) {
        stage64(Arows, sm.s.A, m0, kt, t);
        stage64(Brows, sm.s.B, n0, kt, t);
        __syncthreads();
        MFMA_STEP(acc)
        __syncthreads();
    }
    ACC_TO_EPI(acc)
}

// gemm64_f32src: 64x64 tile of Arows·Bsrc (BOTH fp32 row-major, stride 512),
// staged with inline f2bf; B transposed via scalar scatter. Only A^2 uses
// this (64 blocks).
__device__ inline void gemm64_f32src(const float* __restrict__ Arows,
                                     const float* __restrict__ Bsrc,
                                     int m0, int n0, int t, SqSmem& sm) {
    const int lane = t & 63, w = t >> 6, quad = lane >> 4, l16 = lane & 15;
    const int wm = (w & 1) * 32, wn = (w >> 1) * 32;
    const int r = t >> 2, cq = t & 3;
    f32x4 acc[2][2];
#pragma unroll
    for (int i = 0; i < 2; ++i)
#pragma unroll
        for (int j = 0; j < 2; ++j) acc[i][j] = (f32x4){0.f, 0.f, 0.f, 0.f};
    for (int kt = 0; kt < 8; ++kt) {
        float va[16];
#pragma unroll
        for (int u = 0; u < 4; ++u) {
            float4 f = *(const float4*)&Arows[(size_t)(m0 + r) * 512 + kt * 64 + cq * 16 + u * 4];
            va[u * 4 + 0] = f.x; va[u * 4 + 1] = f.y;
            va[u * 4 + 2] = f.z; va[u * 4 + 3] = f.w;
        }
#pragma unroll
        for (int j2 = 0; j2 < 2; ++j2) {
            us8 h;
#pragma unroll
            for (int j = 0; j < 8; ++j) h[j] = f2bf(va[j2 * 8 + j]);
            int cc = cq * 2 + j2;
            *(us8*)&sm.s.A[r * 64 + (cc ^ (r & 7)) * 8] = h;
        }
#pragma unroll
        for (int u = 0; u < 4; ++u) {
            float4 f = *(const float4*)&Bsrc[(size_t)(kt * 64 + r) * 512 + n0 + cq * 16 + u * 4];
            float vv[4] = {f.x, f.y, f.z, f.w};
#pragma unroll
            for (int j = 0; j < 4; ++j) {
                int n = cq * 16 + u * 4 + j;
                sm.s.B[n * 64 + ((r >> 3) ^ (n & 7)) * 8 + (r & 7)] = f2bf(vv[j]);
            }
        }
        __syncthreads();
        MFMA_STEP(acc)
        __syncthreads();
    }
    ACC_TO_EPI(acc)
}

__device__ inline void epi_out_bf(unsigned short* __restrict__ dst, int m0,
                                  int n0, int t, SqSmem& sm) {
    const int r = t >> 2, cq = t & 3;
    us8 h0, h1;
#pragma unroll
    for (int j = 0; j < 8; ++j) {
        h0[j] = f2bf(sm.epi[r * 68 + cq * 16 + j]);
        h1[j] = f2bf(sm.epi[r * 68 + cq * 16 + 8 + j]);
    }
    *(us8*)&dst[(size_t)(m0 + r) * 512 + n0 + cq * 16]     = h0;
    *(us8*)&dst[(size_t)(m0 + r) * 512 + n0 + cq * 16 + 8] = h1;
}
__device__ inline void epi_out_bfT(unsigned short* __restrict__ dst, int m0,
                                   int n0, int t, SqSmem& sm) {
    const int cf = t >> 2, rq = t & 3;
    us8 o0, o1;
#pragma unroll
    for (int i = 0; i < 8; ++i) {
        o0[i] = f2bf(sm.epi[(rq * 16 + i) * 68 + cf]);
        o1[i] = f2bf(sm.epi[(rq * 16 + 8 + i) * 68 + cf]);
    }
    *(us8*)&dst[(size_t)(n0 + cf) * 512 + m0 + rq * 16]     = o0;
    *(us8*)&dst[(size_t)(n0 + cf) * 512 + m0 + rq * 16 + 8] = o1;
}

// ===========================================================================
// k_s1 (grid 256, unchanged r5): b<64: A2 = f32src(A,A) -> A2_bf,A2T_bf;
// b<128: AT_bf transpose; b>=128: conversions (x_bf, W1_bf, y=b2).
// ===========================================================================
__global__ __launch_bounds__(256) void k_s1(
    const float* __restrict__ A, const float* __restrict__ x,
    const float* __restrict__ W1, const float* __restrict__ b2,
    unsigned short* __restrict__ A2_bf, unsigned short* __restrict__ A2T_bf,
    unsigned short* __restrict__ AT_bf, unsigned short* __restrict__ x_bf,
    unsigned short* __restrict__ W1_bf, float* __restrict__ y) {
    __shared__ SqSmem sm;
    const int b = blockIdx.x, t = threadIdx.x;

    if (b < 64) {
        const int m0 = (b >> 3) * 64, n0 = (b & 7) * 64;
        gemm64_f32src(A, A, m0, n0, t, sm);
        epi_out_bf(A2_bf, m0, n0, t, sm);
        epi_out_bfT(A2T_bf, m0, n0, t, sm);
    } else if (b < 128) {
        const int bb = b - 64, m0 = (bb >> 3) * 64, n0 = (bb & 7) * 64;
        const int r = t >> 2, cq = t & 3;
#pragma unroll
        for (int u = 0; u < 4; ++u) {
            float4 f = *(const float4*)&A[(size_t)(m0 + r) * 512 + n0 + cq * 16 + u * 4];
            sm.epi[r * 68 + cq * 16 + u * 4 + 0] = f.x;
            sm.epi[r * 68 + cq * 16 + u * 4 + 1] = f.y;
            sm.epi[r * 68 + cq * 16 + u * 4 + 2] = f.z;
            sm.epi[r * 68 + cq * 16 + u * 4 + 3] = f.w;
        }
        __syncthreads();
        epi_out_bfT(AT_bf, m0, n0, t, sm);
    } else {
        const int gid = (b - 128) * 256 + t;     // 0 .. 32767
        const float4* x4 = (const float4*)x;
#pragma unroll
        for (int i = 0; i < 8; ++i) {            // x: 262144 chunks
            int id = gid + i * 32768;
            float4 v0 = x4[(size_t)id * 2], v1 = x4[(size_t)id * 2 + 1];
            us8 o;
            o[0] = f2bf(v0.x); o[1] = f2bf(v0.y); o[2] = f2bf(v0.z); o[3] = f2bf(v0.w);
            o[4] = f2bf(v1.x); o[5] = f2bf(v1.y); o[6] = f2bf(v1.z); o[7] = f2bf(v1.w);
            *(us8*)&x_bf[(size_t)id * 8] = o;
        }
        const float4* w4 = (const float4*)W1;
#pragma unroll
        for (int i = 0; i < 4; ++i) {            // W1: 131072 chunks
            int id = gid + i * 32768;
            float4 v0 = w4[(size_t)id * 2], v1 = w4[(size_t)id * 2 + 1];
            us8 o;
            o[0] = f2bf(v0.x); o[1] = f2bf(v0.y); o[2] = f2bf(v0.z); o[3] = f2bf(v0.w);
            o[4] = f2bf(v1.x); o[5] = f2bf(v1.y); o[6] = f2bf(v1.z); o[7] = f2bf(v1.w);
            *(us8*)&W1_bf[(size_t)id * 8] = o;
        }
#pragma unroll
        for (int i = 0; i < 2; ++i) {            // y init: 40960 entries
            int id = gid + i * 32768;
            if (id < B_SZ * DY) y[id] = b2[id % 10];
        }
    }
}

// ===========================================================================
// k_s2 (grid 640, all pure-bf16 gl16 staging):
//   b<64  : A3T = AT·A2T = (A2·A)^T
//   b<128 : A4T = A2T·A2T = (A2·A2)^T    [r5-proven]
//   b<384 : U1  = W1·A  = mfma(W1_bf, AT_bf)
//   else  : U2  = W1·A2 = mfma(W1_bf, A2T_bf)
// ===========================================================================
__global__ __launch_bounds__(256) void k_s2(
    const unsigned short* __restrict__ W1_bf,
    const unsigned short* __restrict__ A_bfx,   // unused (kept for symmetry)
    const unsigned short* __restrict__ A2_bf,
    const unsigned short* __restrict__ A2T_bf,
    const unsigned short* __restrict__ AT_bf,
    unsigned short* __restrict__ A3T_bf, unsigned short* __restrict__ A4T_bf,
    unsigned short* __restrict__ U1_bf, unsigned short* __restrict__ U2_bf) {
    __shared__ SqSmem sm;
    const int b = blockIdx.x, t = threadIdx.x;
    if (b < 64) {
        const int m0 = (b >> 3) * 64, n0 = (b & 7) * 64;
        gemm64_mfma(AT_bf, A2_bf, m0, n0, t, sm);    // AT·A2T = A3T
        epi_out_bf(A3T_bf, m0, n0, t, sm);
    } else if (b < 128) {
        const int bb = b - 64, m0 = (bb >> 3) * 64, n0 = (bb & 7) * 64;
        gemm64_mfma(A2T_bf, A2_bf, m0, n0, t, sm);   // A2T·A2T = A4T
        epi_out_bf(A4T_bf, m0, n0, t, sm);
    } else if (b < 384) {
        const int bb = b - 128, m0 = (bb >> 3) * 64, n0 = (bb & 7) * 64;
        gemm64_mfma(W1_bf, AT_bf, m0, n0, t, sm);    // U1 = W1·A
        epi_out_bf(U1_bf, m0, n0, t, sm);
    } else {
        const int bb = b - 384, m0 = (bb >> 3) * 64, n0 = (bb & 7) * 64;
        gemm64_mfma(W1_bf, A2T_bf, m0, n0, t, sm);   // U2 = W1·A2
        epi_out_bf(U2_bf, m0, n0, t, sm);
    }
}

// ===========================================================================
// k_s3 (grid 256, SINGLE K=512 pass — the r6 work cut):
//   acc = U2·G,  G = c3A + c4A2 + c5A3 + c6A4  (elementwise; GT staged as
//   4-matrix register combine, r4-passed combineB pattern; A-side pure gl16)
//   w1f = W1 + U1 + c2·U2 + acc
//       = W1·(I + A + c2A² + c3A³ + c4A⁴ + c5A⁵ + c6A⁶)
// ===========================================================================
__global__ __launch_bounds__(256) void k_s3(
    const float* __restrict__ W1, const unsigned short* __restrict__ U1_bf,
    const unsigned short* __restrict__ U2_bf,
    const unsigned short* __restrict__ AT_bf,
    const unsigned short* __restrict__ A2T_bf,
    const unsigned short* __restrict__ A3T_bf,
    const unsigned short* __restrict__ A4T_bf,
    unsigned short* __restrict__ w1f) {
    __shared__ SqSmem sm;
    const int b = blockIdx.x, t = threadIdx.x;
    const int m0 = (b >> 3) * 64, n0 = (b & 7) * 64;
    const int lane = t & 63, w = t >> 6, quad = lane >> 4, l16 = lane & 15;
    const int wm = (w & 1) * 32, wn = (w >> 1) * 32;
    f32x4 acc[2][2];
#pragma unroll
    for (int i = 0; i < 2; ++i)
#pragma unroll
        for (int j = 0; j < 2; ++j) acc[i][j] = (f32x4){0.f, 0.f, 0.f, 0.f};

    for (int kt = 0; kt < 8; ++kt) {
        stage64(U2_bf, sm.s.A, m0, kt, t);           // A-side: U2 via gl16
#pragma unroll
        for (int c = 0; c < 2; ++c) {                // B-side: GT combine
            int idx = c * 256 + t, row = idx >> 3, cc = idx & 7;
            int ccs = cc ^ (row & 7);
            size_t ga = (size_t)(n0 + row) * 512 + kt * 64 + cc * 8;
            us8 a1 = *(const us8*)&AT_bf[ga];
            us8 a2 = *(const us8*)&A2T_bf[ga];
            us8 a3 = *(const us8*)&A3T_bf[ga];
            us8 a4 = *(const us8*)&A4T_bf[ga];
            us8 g;
#pragma unroll
            for (int j = 0; j < 8; ++j)
                g[j] = f2bf(C3 * bf2f(a1[j]) + C4 * bf2f(a2[j]) +
                            C5 * bf2f(a3[j]) + C6 * bf2f(a4[j]));
            *(us8*)&sm.s.B[row * 64 + ccs * 8] = g;
        }
        __syncthreads();
        MFMA_STEP(acc)
        __syncthreads();
    }
    ACC_TO_EPI(acc)

    const int r = t >> 2, cq = t & 3;
    size_t gbase = (size_t)(m0 + r) * 512 + n0 + cq * 16;
    us8 u1a = *(const us8*)&U1_bf[gbase], u1b = *(const us8*)&U1_bf[gbase + 8];
    us8 u2a = *(const us8*)&U2_bf[gbase], u2b = *(const us8*)&U2_bf[gbase + 8];
    float4 wa = *(const float4*)&W1[gbase],      wbv = *(const float4*)&W1[gbase + 4];
    float4 wc = *(const float4*)&W1[gbase + 8],  wd  = *(const float4*)&W1[gbase + 12];
    float wf[16] = {wa.x, wa.y, wa.z, wa.w, wbv.x, wbv.y, wbv.z, wbv.w,
                    wc.x, wc.y, wc.z, wc.w, wd.x,  wd.y,  wd.z,  wd.w};
    us8 h0, h1;
#pragma unroll
    for (int j = 0; j < 8; ++j) {
        h0[j] = f2bf(wf[j] + bf2f(u1a[j]) + C2 * bf2f(u2a[j]) +
                     sm.epi[r * 68 + cq * 16 + j]);
        h1[j] = f2bf(wf[8 + j] + bf2f(u1b[j]) + C2 * bf2f(u2b[j]) +
                     sm.epi[r * 68 + cq * 16 + 8 + j]);
    }
    *(us8*)&w1f[gbase]     = h0;
    *(us8*)&w1f[gbase + 8] = h1;
}

// ===========================================================================
// mlp (unchanged r1, proven): 128x128 tiles, grid (32,16), gl16 staging,
// acc[4][4]/wave; epilogue bias+relu -> LDS h, h@W2^T MFMA, atomicAdd y.
// ===========================================================================
union SmemU {
    struct { unsigned short A[128 * 64]; unsigned short B[128 * 64]; } s; // 32 KB
    struct { unsigned short h[128 * 136]; } e;                            // 34.8 KB
};

__global__ __launch_bounds__(256) void mlp_kernel(
    const unsigned short* __restrict__ x_bf,
    const unsigned short* __restrict__ w1f,
    const float* __restrict__ b1, const float* __restrict__ W2,
    float* __restrict__ y) {
    __shared__ SmemU sm;
    const int t    = threadIdx.x;
    const int lane = t & 63, w = t >> 6;
    const int quad = lane >> 4, l16 = lane & 15;
    const int wm = (w & 1) * 64, wn = (w >> 1) * 64;
    const int m0g = blockIdx.x * 128, n0g = blockIdx.y * 128;

    f32x4 acc[4][4];
#pragma unroll
    for (int i = 0; i < 4; ++i)
#pragma unroll
        for (int j = 0; j < 4; ++j) acc[i][j] = (f32x4){0.f, 0.f, 0.f, 0.f};

    for (int kt = 0; kt < 8; ++kt) {
#pragma unroll
        for (int i = 0; i < 4; ++i) {
            int o = w * 256 + i * 64 + lane;
            int row = o >> 3, cc = (o & 7) ^ (row & 7);
            gl16(&x_bf[(size_t)(m0g + row) * 512 + kt * 64 + cc * 8],
                 &sm.s.A[(size_t)(w * 256 + i * 64) * 8]);
        }
#pragma unroll
        for (int i = 0; i < 4; ++i) {
            int o = w * 256 + i * 64 + lane;
            int row = o >> 3, cc = (o & 7) ^ (row & 7);
            gl16(&w1f[(size_t)(n0g + row) * 512 + kt * 64 + cc * 8],
                 &sm.s.B[(size_t)(w * 256 + i * 64) * 8]);
        }
        __syncthreads();
#pragma unroll
        for (int ks = 0; ks < 2; ++ks) {
            bf16x8 af[4], bfr[4];
#pragma unroll
            for (int i = 0; i < 4; ++i) {
                int ra = wm + i * 16 + l16, ca = (ks * 4 + quad) ^ (ra & 7);
                af[i] = *(const bf16x8*)&sm.s.A[ra * 64 + ca * 8];
                int rb = wn + i * 16 + l16, cb = (ks * 4 + quad) ^ (rb & 7);
                bfr[i] = *(const bf16x8*)&sm.s.B[rb * 64 + cb * 8];
            }
#pragma unroll
            for (int i = 0; i < 4; ++i)
#pragma unroll
                for (int j = 0; j < 4; ++j)
                    acc[i][j] = __builtin_amdgcn_mfma_f32_16x16x32_bf16(
                        af[i], bfr[j], acc[i][j], 0, 0, 0);
        }
        __syncthreads();
    }

    float bias[4];
#pragma unroll
    for (int j = 0; j < 4; ++j) bias[j] = b1[n0g + wn + j * 16 + l16];
#pragma unroll
    for (int i = 0; i < 4; ++i)
#pragma unroll
        for (int j = 0; j < 4; ++j)
#pragma unroll
            for (int r = 0; r < 4; ++r) {
                float h = acc[i][j][r] + bias[j];
                h = h > 0.f ? h : 0.f;
                sm.e.h[(wm + i * 16 + quad * 4 + r) * 136 + wn + j * 16 + l16] =
                    f2bf(h);
            }
    __syncthreads();

    {
        bf16x8 wfrag[4];
#pragma unroll
        for (int kc = 0; kc < 4; ++kc) {
            us8 wb;
            if (l16 < DY) {
                const float* wp = &W2[(size_t)l16 * H_SZ + n0g + kc * 32 + quad * 8];
#pragma unroll
                for (int j = 0; j < 8; ++j) wb[j] = f2bf(wp[j]);
            } else {
#pragma unroll
                for (int j = 0; j < 8; ++j) wb[j] = 0;
            }
            wfrag[kc] = *(bf16x8*)&wb;
        }
#pragma unroll
        for (int hh = 0; hh < 2; ++hh) {
            const int mrow = w * 32 + hh * 16;
            f32x4 ay = (f32x4){0.f, 0.f, 0.f, 0.f};
#pragma unroll
            for (int kc = 0; kc < 4; ++kc) {
                bf16x8 af = *(const bf16x8*)&sm.e.h[(mrow + l16) * 136 +
                                                    kc * 32 + quad * 8];
                ay = __builtin_amdgcn_mfma_f32_16x16x32_bf16(af, wfrag[kc], ay,
                                                             0, 0, 0);
            }
            if (l16 < DY) {
#pragma unroll
                for (int r = 0; r < 4; ++r)
                    atomicAdd(&y[(size_t)(m0g + mrow + quad * 4 + r) * DY + l16],
                              ay[r]);
            }
        }
    }
}

// ===========================================================================
extern "C" void kernel_launch(void* const* d_in, const int* in_sizes, int n_in,
                              void* d_out, int out_size, void* d_ws, size_t ws_size,
                              hipStream_t stream) {
    const float* x  = (const float*)d_in[0];
    const float* A  = (const float*)d_in[1];
    const float* W1 = (const float*)d_in[2];
    const float* b1 = (const float*)d_in[3];
    const float* W2 = (const float*)d_in[4];
    const float* b2 = (const float*)d_in[5];
    float* y = (float*)d_out;

    char* ws = (char*)d_ws;
    const size_t HMB = 512u * 1024, MB = 1u << 20;
    unsigned short* AT_bf  = (unsigned short*)(ws);                  // 512 KB
    unsigned short* A2_bf  = (unsigned short*)(ws + 1 * HMB);        // 512 KB
    unsigned short* A2T_bf = (unsigned short*)(ws + 2 * HMB);        // 512 KB
    unsigned short* A3T_bf = (unsigned short*)(ws + 3 * HMB);        // 512 KB
    unsigned short* A4T_bf = (unsigned short*)(ws + 4 * HMB);        // 512 KB
    unsigned short* U1_bf  = (unsigned short*)(ws + 3 * MB);         // 2 MB
    unsigned short* U2_bf  = (unsigned short*)(ws + 5 * MB);         // 2 MB
    unsigned short* w1f    = (unsigned short*)(ws + 7 * MB);         // 2 MB
    unsigned short* W1_bf  = (unsigned short*)(ws + 9 * MB);         // 2 MB
    unsigned short* x_bf   = (unsigned short*)(ws + 11 * MB);        // 4 MB

    k_s1<<<256, 256, 0, stream>>>(A, x, W1, b2, A2_bf, A2T_bf, AT_bf, x_bf,
                                  W1_bf, y);
    k_s2<<<640, 256, 0, stream>>>(W1_bf, nullptr, A2_bf, A2T_bf, AT_bf,
                                  A3T_bf, A4T_bf, U1_bf, U2_bf);
    k_s3<<<256, 256, 0, stream>>>(W1, U1_bf, U2_bf, AT_bf, A2T_bf, A3T_bf,
                                  A4T_bf, w1f);
    mlp_kernel<<<dim3(32, 16), dim3(256), 0, stream>>>(x_bf, w1f, b1, W2, y);
}

// Round 7
// 133.575 us; speedup vs baseline: 2.4429x; 1.0001x over previous
//
#include <hip/hip_runtime.h>
#include <hip/hip_bf16.h>

#define B_SZ 4096
#define DZ   512
#define H_SZ 2048
#define DY   10

// c_k = C(64,k)/64^k  (binomial coefficients of (1+u/64)^64), c0=c1=1
#define C2 0.4921875f
#define C3 0.158935546875f
#define C4 0.037872314453125f
#define C5 ((float)(7624512.0/1073741824.0))
#define C6 ((float)(74974368.0/68719476736.0))

typedef __attribute__((ext_vector_type(8))) __bf16 bf16x8;
typedef __attribute__((ext_vector_type(4))) float  f32x4;
typedef __attribute__((ext_vector_type(8))) unsigned short us8;

__device__ inline unsigned short f2bf(float f) {
    unsigned u = __float_as_uint(f);
    u += 0x7fffu + ((u >> 16) & 1u);   // RTNE
    return (unsigned short)(u >> 16);
}
__device__ inline float bf2f(unsigned short s) {
    return __uint_as_float(((unsigned)s) << 16);
}

// global -> LDS direct 16B copy. LDS dest is wave-uniform base + lane*16
// (HW semantics): callers pre-apply the inverse XOR swizzle on the per-lane
// GLOBAL address and keep the LDS side linear (rule #21 pattern).
// r4 lesson: cross-XCD phase handoff goes at KERNEL boundaries — in-kernel
// grid barriers cost ~70us each in device-scope L2 flush on MI355X.
// r6 lesson: tile-units are ~free (~2us/450); launch boundaries ~6us; kernel
// duration is set by DISPATCH-WAVE count -> pack grids to <= 256 blocks.
__device__ __forceinline__ void gl16(const void* g, void* l) {
    __builtin_amdgcn_global_load_lds(
        (const __attribute__((address_space(1))) unsigned int*)(size_t)g,
        (__attribute__((address_space(3))) unsigned int*)(unsigned)(size_t)l,
        16, 0, 0);
}

// ===== 64x64 tile machinery (16 KB LDS) ====================================
union SqSmem {
    struct { unsigned short A[64 * 64]; unsigned short B[64 * 64]; } s; // 16 KB
    float epi[64 * 68];                                                 // 17.4 KB
};

// Stage a 64x64 bf16 tile into LDS layout lds[row*64 + (cc^(row&7))*8]
// via global_load_lds: linear LDS chunk o -> row=o>>3, src cc=(o&7)^(row&7).
__device__ __forceinline__ void stage64(const unsigned short* __restrict__ src,
                                        unsigned short* lds, int row_base,
                                        int kt, int t) {
    const int w = t >> 6, lane = t & 63;
#pragma unroll
    for (int i = 0; i < 2; ++i) {
        int o = w * 128 + i * 64 + lane;
        int row = o >> 3, cc = (o & 7) ^ (row & 7);
        gl16(&src[(size_t)(row_base + row) * 512 + kt * 64 + cc * 8],
             &lds[(size_t)(w * 128 + i * 64) * 8]);
    }
}

#define MFMA_STEP(acc)                                                        \
    {                                                                         \
        _Pragma("unroll")                                                     \
        for (int ks = 0; ks < 2; ++ks) {                                      \
            bf16x8 af[2], bfr[2];                                             \
            _Pragma("unroll")                                                 \
            for (int i = 0; i < 2; ++i) {                                     \
                int ra = wm + i * 16 + l16, ca = (ks * 4 + quad) ^ (ra & 7);  \
                af[i] = *(const bf16x8*)&sm.s.A[ra * 64 + ca * 8];            \
                int rb = wn + i * 16 + l16, cb = (ks * 4 + quad) ^ (rb & 7);  \
                bfr[i] = *(const bf16x8*)&sm.s.B[rb * 64 + cb * 8];           \
            }                                                                 \
            _Pragma("unroll")                                                 \
            for (int i = 0; i < 2; ++i)                                       \
                _Pragma("unroll")                                             \
                for (int j = 0; j < 2; ++j)                                   \
                    acc[i][j] = __builtin_amdgcn_mfma_f32_16x16x32_bf16(      \
                        af[i], bfr[j], acc[i][j], 0, 0, 0);                   \
        }                                                                     \
    }

#define ACC_TO_EPI(acc)                                                       \
    {                                                                         \
        _Pragma("unroll")                                                     \
        for (int i = 0; i < 2; ++i)                                           \
            _Pragma("unroll")                                                 \
            for (int j = 0; j < 2; ++j)                                       \
                _Pragma("unroll")                                             \
                for (int rr = 0; rr < 4; ++rr)                                \
                    sm.epi[(wm + i * 16 + quad * 4 + rr) * 68 +               \
                           wn + j * 16 + l16] = acc[i][j][rr];                \
        __syncthreads();                                                      \
    }

// gemm64_mfma: 64x64 tile of (Arows)·(Brows)^T, bf16 sources, K=512 -> sm.epi
__device__ inline void gemm64_mfma(const unsigned short* __restrict__ Arows,
                                   const unsigned short* __restrict__ Brows,
                                   int m0, int n0, int t, SqSmem& sm) {
    const int lane = t & 63, w = t >> 6, quad = lane >> 4, l16 = lane & 15;
    const int wm = (w & 1) * 32, wn = (w >> 1) * 32;
    f32x4 acc[2][2];
#pragma unroll
    for (int i = 0; i < 2; ++i)
#pragma unroll
        for (int j = 0; j < 2; ++j) acc[i][j] = (f32x4){0.f, 0.f, 0.f, 0.f};
    for (int kt = 0; kt < 8; ++kt) {
        stage64(Arows, sm.s.A, m0, kt, t);
        stage64(Brows, sm.s.B, n0, kt, t);
        __syncthreads();
        MFMA_STEP(acc)
        __syncthreads();
    }
    ACC_TO_EPI(acc)
}

// gemm64_f32src: 64x64 tile of Arows·Bsrc (BOTH fp32 row-major, stride 512),
// staged with inline f2bf; B transposed via scalar scatter. Only A^2 uses
// this (64 blocks).
__device__ inline void gemm64_f32src(const float* __restrict__ Arows,
                                     const float* __restrict__ Bsrc,
                                     int m0, int n0, int t, SqSmem& sm) {
    const int lane = t & 63, w = t >> 6, quad = lane >> 4, l16 = lane & 15;
    const int wm = (w & 1) * 32, wn = (w >> 1) * 32;
    const int r = t >> 2, cq = t & 3;
    f32x4 acc[2][2];
#pragma unroll
    for (int i = 0; i < 2; ++i)
#pragma unroll
        for (int j = 0; j < 2; ++j) acc[i][j] = (f32x4){0.f, 0.f, 0.f, 0.f};
    for (int kt = 0; kt < 8; ++kt) {
        float va[16];
#pragma unroll
        for (int u = 0; u < 4; ++u) {
            float4 f = *(const float4*)&Arows[(size_t)(m0 + r) * 512 + kt * 64 + cq * 16 + u * 4];
            va[u * 4 + 0] = f.x; va[u * 4 + 1] = f.y;
            va[u * 4 + 2] = f.z; va[u * 4 + 3] = f.w;
        }
#pragma unroll
        for (int j2 = 0; j2 < 2; ++j2) {
            us8 h;
#pragma unroll
            for (int j = 0; j < 8; ++j) h[j] = f2bf(va[j2 * 8 + j]);
            int cc = cq * 2 + j2;
            *(us8*)&sm.s.A[r * 64 + (cc ^ (r & 7)) * 8] = h;
        }
#pragma unroll
        for (int u = 0; u < 4; ++u) {
            float4 f = *(const float4*)&Bsrc[(size_t)(kt * 64 + r) * 512 + n0 + cq * 16 + u * 4];
            float vv[4] = {f.x, f.y, f.z, f.w};
#pragma unroll
            for (int j = 0; j < 4; ++j) {
                int n = cq * 16 + u * 4 + j;
                sm.s.B[n * 64 + ((r >> 3) ^ (n & 7)) * 8 + (r & 7)] = f2bf(vv[j]);
            }
        }
        __syncthreads();
        MFMA_STEP(acc)
        __syncthreads();
    }
    ACC_TO_EPI(acc)
}

__device__ inline void epi_out_bf(unsigned short* __restrict__ dst, int m0,
                                  int n0, int t, SqSmem& sm) {
    const int r = t >> 2, cq = t & 3;
    us8 h0, h1;
#pragma unroll
    for (int j = 0; j < 8; ++j) {
        h0[j] = f2bf(sm.epi[r * 68 + cq * 16 + j]);
        h1[j] = f2bf(sm.epi[r * 68 + cq * 16 + 8 + j]);
    }
    *(us8*)&dst[(size_t)(m0 + r) * 512 + n0 + cq * 16]     = h0;
    *(us8*)&dst[(size_t)(m0 + r) * 512 + n0 + cq * 16 + 8] = h1;
}
__device__ inline void epi_out_bfT(unsigned short* __restrict__ dst, int m0,
                                   int n0, int t, SqSmem& sm) {
    const int cf = t >> 2, rq = t & 3;
    us8 o0, o1;
#pragma unroll
    for (int i = 0; i < 8; ++i) {
        o0[i] = f2bf(sm.epi[(rq * 16 + i) * 68 + cf]);
        o1[i] = f2bf(sm.epi[(rq * 16 + 8 + i) * 68 + cf]);
    }
    *(us8*)&dst[(size_t)(n0 + cf) * 512 + m0 + rq * 16]     = o0;
    *(us8*)&dst[(size_t)(n0 + cf) * 512 + m0 + rq * 16 + 8] = o1;
}

// ===== 128x128 tile for U1/U2 (mlp-proven geometry, 34.8 KB union) =========
union Smem2 {
    SqSmem sq;                                                          // 17.4 KB
    struct { unsigned short A[128 * 64]; unsigned short B[128 * 64]; } s; // 32 KB
    struct { unsigned short h[128 * 136]; } e;                          // 34.8 KB
};

// gemm128_u: 128x128 tile of (Arows)·(Brows)^T, K=512, gl16 staging,
// acc[4][4]/wave; epilogue acc -> bf16 LDS (stride 136) -> coalesced us8 out.
__device__ inline void gemm128_u(const unsigned short* __restrict__ Arows,
                                 const unsigned short* __restrict__ Brows,
                                 int m0, int n0, int t, Smem2& sm,
                                 unsigned short* __restrict__ dst) {
    const int lane = t & 63, w = t >> 6, quad = lane >> 4, l16 = lane & 15;
    const int wm = (w & 1) * 64, wn = (w >> 1) * 64;
    f32x4 acc[4][4];
#pragma unroll
    for (int i = 0; i < 4; ++i)
#pragma unroll
        for (int j = 0; j < 4; ++j) acc[i][j] = (f32x4){0.f, 0.f, 0.f, 0.f};

    for (int kt = 0; kt < 8; ++kt) {
#pragma unroll
        for (int i = 0; i < 4; ++i) {
            int o = w * 256 + i * 64 + lane;
            int row = o >> 3, cc = (o & 7) ^ (row & 7);
            gl16(&Arows[(size_t)(m0 + row) * 512 + kt * 64 + cc * 8],
                 &sm.s.A[(size_t)(w * 256 + i * 64) * 8]);
            gl16(&Brows[(size_t)(n0 + row) * 512 + kt * 64 + cc * 8],
                 &sm.s.B[(size_t)(w * 256 + i * 64) * 8]);
        }
        __syncthreads();
#pragma unroll
        for (int ks = 0; ks < 2; ++ks) {
            bf16x8 af[4], bfr[4];
#pragma unroll
            for (int i = 0; i < 4; ++i) {
                int ra = wm + i * 16 + l16, ca = (ks * 4 + quad) ^ (ra & 7);
                af[i] = *(const bf16x8*)&sm.s.A[ra * 64 + ca * 8];
                int rb = wn + i * 16 + l16, cb = (ks * 4 + quad) ^ (rb & 7);
                bfr[i] = *(const bf16x8*)&sm.s.B[rb * 64 + cb * 8];
            }
#pragma unroll
            for (int i = 0; i < 4; ++i)
#pragma unroll
                for (int j = 0; j < 4; ++j)
                    acc[i][j] = __builtin_amdgcn_mfma_f32_16x16x32_bf16(
                        af[i], bfr[j], acc[i][j], 0, 0, 0);
        }
        __syncthreads();
    }

    // acc -> bf16 LDS (mlp-proven pattern)
#pragma unroll
    for (int i = 0; i < 4; ++i)
#pragma unroll
        for (int j = 0; j < 4; ++j)
#pragma unroll
            for (int r = 0; r < 4; ++r)
                sm.e.h[(wm + i * 16 + quad * 4 + r) * 136 + wn + j * 16 + l16] =
                    f2bf(acc[i][j][r]);
    __syncthreads();

    // coalesced out: 128 rows x 16 us8-chunks = 2048 chunks / 256 thr = 8 ea
#pragma unroll
    for (int c8 = 0; c8 < 8; ++c8) {
        int chunk = c8 * 256 + t;
        int rr = chunk >> 4, cc8 = (chunk & 15) * 8;
        us8 h = *(const us8*)&sm.e.h[rr * 136 + cc8];
        *(us8*)&dst[(size_t)(m0 + rr) * 512 + n0 + cc8] = h;
    }
}

// ===========================================================================
// k_s1 (grid 256, unchanged r6): b<64: A2 = f32src(A,A) -> A2_bf,A2T_bf;
// b<128: AT_bf transpose; b>=128: conversions (x_bf, W1_bf, y=b2).
// ===========================================================================
__global__ __launch_bounds__(256) void k_s1(
    const float* __restrict__ A, const float* __restrict__ x,
    const float* __restrict__ W1, const float* __restrict__ b2,
    unsigned short* __restrict__ A2_bf, unsigned short* __restrict__ A2T_bf,
    unsigned short* __restrict__ AT_bf, unsigned short* __restrict__ x_bf,
    unsigned short* __restrict__ W1_bf, float* __restrict__ y) {
    __shared__ SqSmem sm;
    const int b = blockIdx.x, t = threadIdx.x;

    if (b < 64) {
        const int m0 = (b >> 3) * 64, n0 = (b & 7) * 64;
        gemm64_f32src(A, A, m0, n0, t, sm);
        epi_out_bf(A2_bf, m0, n0, t, sm);
        epi_out_bfT(A2T_bf, m0, n0, t, sm);
    } else if (b < 128) {
        const int bb = b - 64, m0 = (bb >> 3) * 64, n0 = (bb & 7) * 64;
        const int r = t >> 2, cq = t & 3;
#pragma unroll
        for (int u = 0; u < 4; ++u) {
            float4 f = *(const float4*)&A[(size_t)(m0 + r) * 512 + n0 + cq * 16 + u * 4];
            sm.epi[r * 68 + cq * 16 + u * 4 + 0] = f.x;
            sm.epi[r * 68 + cq * 16 + u * 4 + 1] = f.y;
            sm.epi[r * 68 + cq * 16 + u * 4 + 2] = f.z;
            sm.epi[r * 68 + cq * 16 + u * 4 + 3] = f.w;
        }
        __syncthreads();
        epi_out_bfT(AT_bf, m0, n0, t, sm);
    } else {
        const int gid = (b - 128) * 256 + t;     // 0 .. 32767
        const float4* x4 = (const float4*)x;
#pragma unroll
        for (int i = 0; i < 8; ++i) {            // x: 262144 chunks
            int id = gid + i * 32768;
            float4 v0 = x4[(size_t)id * 2], v1 = x4[(size_t)id * 2 + 1];
            us8 o;
            o[0] = f2bf(v0.x); o[1] = f2bf(v0.y); o[2] = f2bf(v0.z); o[3] = f2bf(v0.w);
            o[4] = f2bf(v1.x); o[5] = f2bf(v1.y); o[6] = f2bf(v1.z); o[7] = f2bf(v1.w);
            *(us8*)&x_bf[(size_t)id * 8] = o;
        }
        const float4* w4 = (const float4*)W1;
#pragma unroll
        for (int i = 0; i < 4; ++i) {            // W1: 131072 chunks
            int id = gid + i * 32768;
            float4 v0 = w4[(size_t)id * 2], v1 = w4[(size_t)id * 2 + 1];
            us8 o;
            o[0] = f2bf(v0.x); o[1] = f2bf(v0.y); o[2] = f2bf(v0.z); o[3] = f2bf(v0.w);
            o[4] = f2bf(v1.x); o[5] = f2bf(v1.y); o[6] = f2bf(v1.z); o[7] = f2bf(v1.w);
            *(us8*)&W1_bf[(size_t)id * 8] = o;
        }
#pragma unroll
        for (int i = 0; i < 2; ++i) {            // y init: 40960 entries
            int id = gid + i * 32768;
            if (id < B_SZ * DY) y[id] = b2[id % 10];
        }
    }
}

// ===========================================================================
// k_s2 (grid 256 = ONE dispatch wave; r7 repack of r6's 640 blocks):
//   b<64   : A3T = AT·A2T  (64² path)
//   b<128  : A4T = A2T·A2T (64² path)
//   b<192  : U1  = W1·A    (128² tiles: 16 m x 4 n)
//   else   : U2  = W1·A2   (128² tiles)
// ===========================================================================
__global__ __launch_bounds__(256) void k_s2(
    const unsigned short* __restrict__ W1_bf,
    const unsigned short* __restrict__ A2_bf,
    const unsigned short* __restrict__ A2T_bf,
    const unsigned short* __restrict__ AT_bf,
    unsigned short* __restrict__ A3T_bf, unsigned short* __restrict__ A4T_bf,
    unsigned short* __restrict__ U1_bf, unsigned short* __restrict__ U2_bf) {
    __shared__ Smem2 sm;
    const int b = blockIdx.x, t = threadIdx.x;
    if (b < 64) {
        const int m0 = (b >> 3) * 64, n0 = (b & 7) * 64;
        gemm64_mfma(AT_bf, A2_bf, m0, n0, t, sm.sq);     // AT·A2T = A3T
        epi_out_bf(A3T_bf, m0, n0, t, sm.sq);
    } else if (b < 128) {
        const int bb = b - 64, m0 = (bb >> 3) * 64, n0 = (bb & 7) * 64;
        gemm64_mfma(A2T_bf, A2_bf, m0, n0, t, sm.sq);    // A2T·A2T = A4T
        epi_out_bf(A4T_bf, m0, n0, t, sm.sq);
    } else if (b < 192) {
        const int bb = b - 128, m0 = (bb >> 2) * 128, n0 = (bb & 3) * 128;
        gemm128_u(W1_bf, AT_bf, m0, n0, t, sm, U1_bf);   // U1 = W1·A
    } else {
        const int bb = b - 192, m0 = (bb >> 2) * 128, n0 = (bb & 3) * 128;
        gemm128_u(W1_bf, A2T_bf, m0, n0, t, sm, U2_bf);  // U2 = W1·A2
    }
}

// ===========================================================================
// k_s3 (grid 256, unchanged r6): single K=512 pass:
//   acc = U2·G,  G = c3A + c4A2 + c5A3 + c6A4  (elementwise B-combine)
//   w1f = W1 + U1 + c2·U2 + acc
// ===========================================================================
__global__ __launch_bounds__(256) void k_s3(
    const float* __restrict__ W1, const unsigned short* __restrict__ U1_bf,
    const unsigned short* __restrict__ U2_bf,
    const unsigned short* __restrict__ AT_bf,
    const unsigned short* __restrict__ A2T_bf,
    const unsigned short* __restrict__ A3T_bf,
    const unsigned short* __restrict__ A4T_bf,
    unsigned short* __restrict__ w1f) {
    __shared__ SqSmem sm;
    const int b = blockIdx.x, t = threadIdx.x;
    const int m0 = (b >> 3) * 64, n0 = (b & 7) * 64;
    const int lane = t & 63, w = t >> 6, quad = lane >> 4, l16 = lane & 15;
    const int wm = (w & 1) * 32, wn = (w >> 1) * 32;
    f32x4 acc[2][2];
#pragma unroll
    for (int i = 0; i < 2; ++i)
#pragma unroll
        for (int j = 0; j < 2; ++j) acc[i][j] = (f32x4){0.f, 0.f, 0.f, 0.f};

    for (int kt = 0; kt < 8; ++kt) {
        stage64(U2_bf, sm.s.A, m0, kt, t);           // A-side: U2 via gl16
#pragma unroll
        for (int c = 0; c < 2; ++c) {                // B-side: GT combine
            int idx = c * 256 + t, row = idx >> 3, cc = idx & 7;
            int ccs = cc ^ (row & 7);
            size_t ga = (size_t)(n0 + row) * 512 + kt * 64 + cc * 8;
            us8 a1 = *(const us8*)&AT_bf[ga];
            us8 a2 = *(const us8*)&A2T_bf[ga];
            us8 a3 = *(const us8*)&A3T_bf[ga];
            us8 a4 = *(const us8*)&A4T_bf[ga];
            us8 g;
#pragma unroll
            for (int j = 0; j < 8; ++j)
                g[j] = f2bf(C3 * bf2f(a1[j]) + C4 * bf2f(a2[j]) +
                            C5 * bf2f(a3[j]) + C6 * bf2f(a4[j]));
            *(us8*)&sm.s.B[row * 64 + ccs * 8] = g;
        }
        __syncthreads();
        MFMA_STEP(acc)
        __syncthreads();
    }
    ACC_TO_EPI(acc)

    const int r = t >> 2, cq = t & 3;
    size_t gbase = (size_t)(m0 + r) * 512 + n0 + cq * 16;
    us8 u1a = *(const us8*)&U1_bf[gbase], u1b = *(const us8*)&U1_bf[gbase + 8];
    us8 u2a = *(const us8*)&U2_bf[gbase], u2b = *(const us8*)&U2_bf[gbase + 8];
    float4 wa = *(const float4*)&W1[gbase],      wbv = *(const float4*)&W1[gbase + 4];
    float4 wc = *(const float4*)&W1[gbase + 8],  wd  = *(const float4*)&W1[gbase + 12];
    float wf[16] = {wa.x, wa.y, wa.z, wa.w, wbv.x, wbv.y, wbv.z, wbv.w,
                    wc.x, wc.y, wc.z, wc.w, wd.x,  wd.y,  wd.z,  wd.w};
    us8 h0, h1;
#pragma unroll
    for (int j = 0; j < 8; ++j) {
        h0[j] = f2bf(wf[j] + bf2f(u1a[j]) + C2 * bf2f(u2a[j]) +
                     sm.epi[r * 68 + cq * 16 + j]);
        h1[j] = f2bf(wf[8 + j] + bf2f(u1b[j]) + C2 * bf2f(u2b[j]) +
                     sm.epi[r * 68 + cq * 16 + 8 + j]);
    }
    *(us8*)&w1f[gbase]     = h0;
    *(us8*)&w1f[gbase + 8] = h1;
}

// ===========================================================================
// mlp (unchanged r1, proven): 128x128 tiles, grid (32,16), gl16 staging,
// acc[4][4]/wave; epilogue bias+relu -> LDS h, h@W2^T MFMA, atomicAdd y.
// ===========================================================================
union SmemU {
    struct { unsigned short A[128 * 64]; unsigned short B[128 * 64]; } s; // 32 KB
    struct { unsigned short h[128 * 136]; } e;                            // 34.8 KB
};

__global__ __launch_bounds__(256) void mlp_kernel(
    const unsigned short* __restrict__ x_bf,
    const unsigned short* __restrict__ w1f,
    const float* __restrict__ b1, const float* __restrict__ W2,
    float* __restrict__ y) {
    __shared__ SmemU sm;
    const int t    = threadIdx.x;
    const int lane = t & 63, w = t >> 6;
    const int quad = lane >> 4, l16 = lane & 15;
    const int wm = (w & 1) * 64, wn = (w >> 1) * 64;
    const int m0g = blockIdx.x * 128, n0g = blockIdx.y * 128;

    f32x4 acc[4][4];
#pragma unroll
    for (int i = 0; i < 4; ++i)
#pragma unroll
        for (int j = 0; j < 4; ++j) acc[i][j] = (f32x4){0.f, 0.f, 0.f, 0.f};

    for (int kt = 0; kt < 8; ++kt) {
#pragma unroll
        for (int i = 0; i < 4; ++i) {
            int o = w * 256 + i * 64 + lane;
            int row = o >> 3, cc = (o & 7) ^ (row & 7);
            gl16(&x_bf[(size_t)(m0g + row) * 512 + kt * 64 + cc * 8],
                 &sm.s.A[(size_t)(w * 256 + i * 64) * 8]);
        }
#pragma unroll
        for (int i = 0; i < 4; ++i) {
            int o = w * 256 + i * 64 + lane;
            int row = o >> 3, cc = (o & 7) ^ (row & 7);
            gl16(&w1f[(size_t)(n0g + row) * 512 + kt * 64 + cc * 8],
                 &sm.s.B[(size_t)(w * 256 + i * 64) * 8]);
        }
        __syncthreads();
#pragma unroll
        for (int ks = 0; ks < 2; ++ks) {
            bf16x8 af[4], bfr[4];
#pragma unroll
            for (int i = 0; i < 4; ++i) {
                int ra = wm + i * 16 + l16, ca = (ks * 4 + quad) ^ (ra & 7);
                af[i] = *(const bf16x8*)&sm.s.A[ra * 64 + ca * 8];
                int rb = wn + i * 16 + l16, cb = (ks * 4 + quad) ^ (rb & 7);
                bfr[i] = *(const bf16x8*)&sm.s.B[rb * 64 + cb * 8];
            }
#pragma unroll
            for (int i = 0; i < 4; ++i)
#pragma unroll
                for (int j = 0; j < 4; ++j)
                    acc[i][j] = __builtin_amdgcn_mfma_f32_16x16x32_bf16(
                        af[i], bfr[j], acc[i][j], 0, 0, 0);
        }
        __syncthreads();
    }

    float bias[4];
#pragma unroll
    for (int j = 0; j < 4; ++j) bias[j] = b1[n0g + wn + j * 16 + l16];
#pragma unroll
    for (int i = 0; i < 4; ++i)
#pragma unroll
        for (int j = 0; j < 4; ++j)
#pragma unroll
            for (int r = 0; r < 4; ++r) {
                float h = acc[i][j][r] + bias[j];
                h = h > 0.f ? h : 0.f;
                sm.e.h[(wm + i * 16 + quad * 4 + r) * 136 + wn + j * 16 + l16] =
                    f2bf(h);
            }
    __syncthreads();

    {
        bf16x8 wfrag[4];
#pragma unroll
        for (int kc = 0; kc < 4; ++kc) {
            us8 wb;
            if (l16 < DY) {
                const float* wp = &W2[(size_t)l16 * H_SZ + n0g + kc * 32 + quad * 8];
#pragma unroll
                for (int j = 0; j < 8; ++j) wb[j] = f2bf(wp[j]);
            } else {
#pragma unroll
                for (int j = 0; j < 8; ++j) wb[j] = 0;
            }
            wfrag[kc] = *(bf16x8*)&wb;
        }
#pragma unroll
        for (int hh = 0; hh < 2; ++hh) {
            const int mrow = w * 32 + hh * 16;
            f32x4 ay = (f32x4){0.f, 0.f, 0.f, 0.f};
#pragma unroll
            for (int kc = 0; kc < 4; ++kc) {
                bf16x8 af = *(const bf16x8*)&sm.e.h[(mrow + l16) * 136 +
                                                    kc * 32 + quad * 8];
                ay = __builtin_amdgcn_mfma_f32_16x16x32_bf16(af, wfrag[kc], ay,
                                                             0, 0, 0);
            }
            if (l16 < DY) {
#pragma unroll
                for (int r = 0; r < 4; ++r)
                    atomicAdd(&y[(size_t)(m0g + mrow + quad * 4 + r) * DY + l16],
                              ay[r]);
            }
        }
    }
}

// ===========================================================================
extern "C" void kernel_launch(void* const* d_in, const int* in_sizes, int n_in,
                              void* d_out, int out_size, void* d_ws, size_t ws_size,
                              hipStream_t stream) {
    const float* x  = (const float*)d_in[0];
    const float* A  = (const float*)d_in[1];
    const float* W1 = (const float*)d_in[2];
    const float* b1 = (const float*)d_in[3];
    const float* W2 = (const float*)d_in[4];
    const float* b2 = (const float*)d_in[5];
    float* y = (float*)d_out;

    char* ws = (char*)d_ws;
    const size_t HMB = 512u * 1024, MB = 1u << 20;
    unsigned short* AT_bf  = (unsigned short*)(ws);                  // 512 KB
    unsigned short* A2_bf  = (unsigned short*)(ws + 1 * HMB);        // 512 KB
    unsigned short* A2T_bf = (unsigned short*)(ws + 2 * HMB);        // 512 KB
    unsigned short* A3T_bf = (unsigned short*)(ws + 3 * HMB);        // 512 KB
    unsigned short* A4T_bf = (unsigned short*)(ws + 4 * HMB);        // 512 KB
    unsigned short* U1_bf  = (unsigned short*)(ws + 3 * MB);         // 2 MB
    unsigned short* U2_bf  = (unsigned short*)(ws + 5 * MB);         // 2 MB
    unsigned short* w1f    = (unsigned short*)(ws + 7 * MB);         // 2 MB
    unsigned short* W1_bf  = (unsigned short*)(ws + 9 * MB);         // 2 MB
    unsigned short* x_bf   = (unsigned short*)(ws + 11 * MB);        // 4 MB

    k_s1<<<256, 256, 0, stream>>>(A, x, W1, b2, A2_bf, A2T_bf, AT_bf, x_bf,
                                  W1_bf, y);
    k_s2<<<256, 256, 0, stream>>>(W1_bf, A2_bf, A2T_bf, AT_bf, A3T_bf,
                                  A4T_bf, U1_bf, U2_bf);
    k_s3<<<256, 256, 0, stream>>>(W1, U1_bf, U2_bf, AT_bf, A2T_bf, A3T_bf,
                                  A4T_bf, w1f);
    mlp_kernel<<<dim3(32, 16), dim3(256), 0, stream>>>(x_bf, w1f, b1, W2, y);
}